// Round 2
// baseline (372.435 us; speedup 1.0000x reference)
//
#include <hip/hip_runtime.h>

#define S_LEN 2048
#define HID   2048
#define NQH   32
#define NKV   8
#define HD    64

#define BM 256
#define BN 256
#define BK 64
#define NTILES (HID / BK)   // 32

typedef __bf16 bf16x8 __attribute__((ext_vector_type(8)));
typedef __bf16 bf16x4 __attribute__((ext_vector_type(4)));
typedef float  f32x4  __attribute__((ext_vector_type(4)));

#define MFMA16(a, b, c) __builtin_amdgcn_mfma_f32_16x16x32_bf16(a, b, c, 0, 0, 0)

__device__ __forceinline__ void async_copy16(const void* g, void* l) {
  __builtin_amdgcn_global_load_lds(
      (const __attribute__((address_space(1))) unsigned int*)g,
      (__attribute__((address_space(3))) unsigned int*)l, 16, 0, 0);
}

#define FENCE asm volatile("" ::: "memory")
#define BARRIER do { FENCE; __builtin_amdgcn_s_barrier(); FENCE; } while (0)

// ---------------- fused f32 -> bf16 cast of x + all weights ----------------
__global__ void cast_all_k(const float* __restrict__ x,  const float* __restrict__ wq,
                           const float* __restrict__ wk, const float* __restrict__ wv,
                           const float* __restrict__ wo,
                           __bf16* __restrict__ xb,  __bf16* __restrict__ wqb,
                           __bf16* __restrict__ wkb, __bf16* __restrict__ wvb,
                           __bf16* __restrict__ wob) {
  int bid = blockIdx.x;
  const float* in; __bf16* out; int base;
  if (bid < 8192)       { in = x;  out = xb;  base = bid; }
  else if (bid < 12288) { in = wq; out = wqb; base = bid - 8192; }
  else if (bid < 13312) { in = wk; out = wkb; base = bid - 12288; }
  else if (bid < 14336) { in = wv; out = wvb; base = bid - 13312; }
  else                  { in = wo; out = wob; base = bid - 14336; }
  int i = (base * 256 + threadIdx.x) * 4;
  float4 v = *(const float4*)(in + i);
  bf16x4 o;
  o[0] = (__bf16)v.x; o[1] = (__bf16)v.y; o[2] = (__bf16)v.z; o[3] = (__bf16)v.w;
  *(bf16x4*)(out + i) = o;
}

// ---------------- 256x256 8-phase GEMM core: acc = A[M,K] * B[N,K]^T ----------------
// 512 threads / 8 waves as 2(M)x4(N); per-wave output 128x64 (mt 0..7, nt 0..3).
// LDS: 2 x (256x64) per matrix = 128 KiB, double-buffered, XOR-swizzled (T2).
// Per K-tile: 4 phase-pairs {ds_read subtile; barrier; setprio+16 MFMA; barrier}.
// All 8 stage loads for tile t+1 issued at tile t phase 0 (~2400 cyc cover);
// single counted vmcnt(0) at phase 3 (long-distance, no short drain).
__device__ __forceinline__ void gemm_pipe(const __bf16* __restrict__ A,
                                          const __bf16* __restrict__ B,
                                          int m0, int n0, int K,
                                          __bf16 (&As)[2][BM][BK],
                                          __bf16 (&Bs)[2][BN][BK],
                                          f32x4 (&acc)[8][4]) {
  const int tid = threadIdx.x, wave = tid >> 6, lane = tid & 63;
  const int l15 = lane & 15, quad = lane >> 4;
  const int wr = wave >> 2, wc = wave & 3;

  // staging map: thread -> (row = wave*8 + lane>>3 within each 64-row sweep,
  // chunk = lane&7); global source column pre-swizzled by row&7 (T2, rule #21).
  const int srow8 = lane >> 3;
  const int scol  = ((lane & 7) ^ srow8) * 8;
  const __bf16* gA = A + (size_t)(m0 + wave * 8 + srow8) * K + scol;
  const __bf16* gB = B + (size_t)(n0 + wave * 8 + srow8) * K + scol;

  // ds_read chunk offsets: chunk = (kk*4+quad) ^ (row&7), row&7 == l15&7
  const int c0 = ((quad)     ^ (l15 & 7)) * 8;
  const int c1 = ((4 + quad) ^ (l15 & 7)) * 8;

#define STAGE8(sb, kt) do {                                                          \
    _Pragma("unroll")                                                                \
    for (int sw = 0; sw < 4; sw++)                                                   \
      async_copy16(gA + (kt) + (size_t)(sw * 64) * K, &As[sb][sw * 64 + wave * 8][0]); \
    _Pragma("unroll")                                                                \
    for (int sw = 0; sw < 4; sw++)                                                   \
      async_copy16(gB + (kt) + (size_t)(sw * 64) * K, &Bs[sb][sw * 64 + wave * 8][0]); \
  } while (0)

  STAGE8(0, 0);
  asm volatile("s_waitcnt vmcnt(0)" ::: "memory");
  BARRIER;

  int s = 0;
#pragma unroll 1
  for (int t = 0; t < NTILES; t++) {
    const __bf16* a0 = &As[s][wr * 128][0];
    const __bf16* b0 = &Bs[s][wc * 64][0];

    // issue next tile's loads into the buffer freed at the last barrier
    if (t + 1 < NTILES) STAGE8(s ^ 1, (t + 1) * BK);

    bf16x8 bfr[4][2], af[2][2];
#pragma unroll
    for (int nt = 0; nt < 4; nt++) {
      bfr[nt][0] = *(const bf16x8*)(b0 + (nt * 16 + l15) * BK + c0);
      bfr[nt][1] = *(const bf16x8*)(b0 + (nt * 16 + l15) * BK + c1);
    }

#pragma unroll
    for (int mp = 0; mp < 4; mp++) {
#pragma unroll
      for (int m2 = 0; m2 < 2; m2++) {
        af[m2][0] = *(const bf16x8*)(a0 + ((mp * 2 + m2) * 16 + l15) * BK + c0);
        af[m2][1] = *(const bf16x8*)(a0 + ((mp * 2 + m2) * 16 + l15) * BK + c1);
      }
      if (mp == 3 && t + 1 < NTILES)
        asm volatile("s_waitcnt vmcnt(0)" ::: "memory");  // next buffer ready (issued ~3 phases ago)
      BARRIER;
      __builtin_amdgcn_s_setprio(1);
#pragma unroll
      for (int m2 = 0; m2 < 2; m2++)
#pragma unroll
        for (int nt = 0; nt < 4; nt++)
#pragma unroll
          for (int kk = 0; kk < 2; kk++)
            acc[mp * 2 + m2][nt] = MFMA16(af[m2][kk], bfr[nt][kk], acc[mp * 2 + m2][nt]);
      __builtin_amdgcn_s_setprio(0);
      BARRIER;
    }
    s ^= 1;
  }
#undef STAGE8
}

// fused QKV projection + RoPE(Q,K) + V transpose. grid (16, 12), 512 thr
__global__ __launch_bounds__(512, 2) void gemm_qkv_k(const __bf16* __restrict__ xb,
    const __bf16* __restrict__ wqb, const __bf16* __restrict__ wkb, const __bf16* __restrict__ wvb,
    const float* __restrict__ bq, const float* __restrict__ bk, const float* __restrict__ bv,
    const float* __restrict__ fr,
    __bf16* __restrict__ Qb, __bf16* __restrict__ Kb, __bf16* __restrict__ Vt) {
  __shared__ __align__(16) __bf16 As[2][BM][BK];
  __shared__ __align__(16) __bf16 Bs[2][BN][BK];
  const int by = blockIdx.y;
  const int m0 = blockIdx.x * BM;
  const __bf16* B; const float* bias; int n0;
  int mode;  // 0 = ropeQ, 1 = ropeK, 2 = vtrans
  if (by < 8)       { B = wqb; bias = bq; n0 = by * 256;        mode = 0; }
  else if (by < 10) { B = wkb; bias = bk; n0 = (by - 8) * 256;  mode = 1; }
  else              { B = wvb; bias = bv; n0 = (by - 10) * 256; mode = 2; }

  f32x4 acc[8][4] = {};
  gemm_pipe(xb, B, m0, n0, HID, As, Bs, acc);

  const int tid = threadIdx.x, wave = tid >> 6, lane = tid & 63;
  const int l15 = lane & 15, quad = lane >> 4;
  const int wr = wave >> 2, wc = wave & 3;

  if (mode == 2) {
#pragma unroll
    for (int nt = 0; nt < 4; nt++) {
      int col = n0 + wc * 64 + nt * 16 + l15;       // 0..511
      int g = col >> 6, d = col & 63;
      float bv2 = bias[col];
#pragma unroll
      for (int mt = 0; mt < 8; mt++) {
        int row = m0 + wr * 128 + mt * 16 + quad * 4;
        int b = row >> 11, sI = row & 2047;
        bf16x4 o;
#pragma unroll
        for (int r = 0; r < 4; r++) o[r] = (__bf16)(acc[mt][nt][r] + bv2);
        *(bf16x4*)(Vt + (((size_t)(b * NKV + g) * HD + d)) * S_LEN + sI) = o;
      }
    }
  } else {
    const float scale = (mode == 0) ? 0.125f * 1.44269504f : 1.0f;
    const int ldc = (mode == 0) ? HID : 512;
    __bf16* C = (mode == 0) ? Qb : Kb;
    const int dpar = l15 & 1;
#pragma unroll
    for (int nt = 0; nt < 4; nt++) {
      int col = n0 + wc * 64 + nt * 16 + l15;
      int d = col & 63;
      float bv2 = bias[col];
#pragma unroll
      for (int mt = 0; mt < 8; mt++) {
        int row = m0 + wr * 128 + mt * 16 + quad * 4;
        int sI = row & 2047;
#pragma unroll
        for (int r = 0; r < 4; r++) {
          float v = acc[mt][nt][r] + bv2;
          float p = __shfl_xor(v, 1, 64);
          float f = fr[(size_t)(sI + r) * HD + d];
          float fp = __shfl_xor(f, 1, 64);
          float o = dpar ? (p * f + v * fp) : (v * f - p * fp);
          C[(size_t)(row + r) * ldc + col] = (__bf16)(o * scale);
        }
      }
    }
  }
}

// output projection: grid (16, 8), 512 thr
__global__ __launch_bounds__(512, 2) void gemm_out_k(const __bf16* __restrict__ A,
    const __bf16* __restrict__ Bw, const float* __restrict__ bias, float* __restrict__ C) {
  __shared__ __align__(16) __bf16 As[2][BM][BK];
  __shared__ __align__(16) __bf16 Bs[2][BN][BK];
  const int m0 = blockIdx.x * BM, n0 = blockIdx.y * BN;
  f32x4 acc[8][4] = {};
  gemm_pipe(A, Bw, m0, n0, HID, As, Bs, acc);
  const int tid = threadIdx.x, wave = tid >> 6, lane = tid & 63;
  const int l15 = lane & 15, quad = lane >> 4;
  const int wr = wave >> 2, wc = wave & 3;
#pragma unroll
  for (int nt = 0; nt < 4; nt++) {
    int col = n0 + wc * 64 + nt * 16 + l15;
    float bv = bias[col];
#pragma unroll
    for (int mt = 0; mt < 8; mt++) {
      int row = m0 + wr * 128 + mt * 16 + quad * 4;
#pragma unroll
      for (int r = 0; r < 4; r++)
        C[(size_t)(row + r) * HID + col] = acc[mt][nt][r] + bv;
    }
  }
}

// ---------------- Flash attention v6: uniform-work blocks ----------------
// 64-row q-tiles (32 tiles). Block y processes the PAIR (qt=y, qt=31-y):
// kv-iters = (y+1)+(32-y) = 33 for EVERY block -> zero drain tail at 4 blocks/CU.
// 4 waves x 16 q-rows; no-max softmax (exp2, Q pre-scaled log2e/8); rsum via
// ones-MFMA; swizzled LDS, XOR-decomposed addresses.
__global__ __launch_bounds__(256, 4) void flash_k(const __bf16* __restrict__ Q,
                                                  const __bf16* __restrict__ K,
                                                  const __bf16* __restrict__ Vt,
                                                  __bf16* __restrict__ O) {
  __shared__ __align__(64) __bf16 Ksm[64][64];       // [kv][d] swizzled (key=row&7)
  __shared__ __align__(64) __bf16 Vsm[64][64];       // [d][kv] swizzled
  __shared__ __align__(64) __bf16 Psm[4][16][64];    // per-wave [q][kv] swizzled
  const int tid = threadIdx.x;
  const int wave = tid >> 6, lane = tid & 63;
  const int l15 = lane & 15, quad = lane >> 4;
  const int x7 = l15 & 7, l15h = l15 >> 3;
  const int bh = blockIdx.x;
  const int b = bh >> 5, h = bh & 31, g = h >> 2;

  const int srow = tid >> 2, sc = (tid & 3) * 16;
  const int r7 = srow & 7;
  const int w0 = (((sc >> 3))     ^ r7) * 8;
  const int w1 = (((sc >> 3) + 1) ^ r7) * 8;

  char* kbp = (char*)&Ksm[0][0];
  char* vbp = (char*)&Vsm[0][0];
  char* pbp = (char*)&Psm[0][0][0];
  int kr[2], pr[2], pw[4];
#pragma unroll
  for (int ks = 0; ks < 2; ks++) {
    kr[ks] = l15 * 128 + (((ks * 4 + quad) ^ x7) * 16);
    pr[ks] = wave * 2048 + kr[ks];
  }
#pragma unroll
  for (int nt = 0; nt < 4; nt++)
    pw[nt] = wave * 2048 + quad * 512 + x7 * 2 + (((2 * nt + l15h) ^ ((quad & 1) * 4)) * 16);

  bf16x8 ones;
#pragma unroll
  for (int j = 0; j < 8; j++) ones[j] = (__bf16)1.0f;

  const __bf16* kbase = K + ((size_t)b * S_LEN + srow) * (NKV * HD) + g * HD + sc;
  const __bf16* vbase = Vt + (((size_t)b * NKV + g) * HD + srow) * S_LEN + sc;

#pragma unroll 1
  for (int half = 0; half < 2; half++) {
    const int qt = half ? (31 - (int)blockIdx.y) : (int)blockIdx.y;
    const int wq0 = qt * 64 + wave * 16;

    const __bf16* qp = Q + ((size_t)(b * S_LEN + wq0 + l15)) * HID + h * HD + quad * 8;
    bf16x8 qf0 = *(const bf16x8*)qp;
    bf16x8 qf1 = *(const bf16x8*)(qp + 32);

    f32x4 acc[4] = {};
    f32x4 accs = {};

    const __bf16* kp = kbase;
    const __bf16* vp = vbase;
    uint4 k0 = *(const uint4*)kp, k1 = *(const uint4*)(kp + 8);
    uint4 v0 = *(const uint4*)vp, v1 = *(const uint4*)(vp + 8);

    for (int t = 0; t <= qt; t++) {
      const int kv0 = t * 64;
      __syncthreads();
      *(uint4*)&Ksm[srow][w0] = k0;
      *(uint4*)&Ksm[srow][w1] = k1;
      *(uint4*)&Vsm[srow][w0] = v0;
      *(uint4*)&Vsm[srow][w1] = v1;
      if (t < qt) {
        kp += 64 * NKV * HD;  vp += 64;
        k0 = *(const uint4*)kp; k1 = *(const uint4*)(kp + 8);
        v0 = *(const uint4*)vp; v1 = *(const uint4*)(vp + 8);
      }
      __syncthreads();

      if (kv0 > wq0 + 15) continue;   // fully masked for this wave

      bf16x8 kf[2][4];
#pragma unroll
      for (int ks = 0; ks < 2; ks++)
#pragma unroll
        for (int nt = 0; nt < 4; nt++)
          kf[ks][nt] = *(const bf16x8*)(kbp + (kr[ks] + nt * 2048));

      f32x4 sacc[4] = {};
#pragma unroll
      for (int nt = 0; nt < 4; nt++) {
        sacc[nt] = MFMA16(qf0, kf[0][nt], sacc[nt]);
        sacc[nt] = MFMA16(qf1, kf[1][nt], sacc[nt]);
      }
      const bool domask = (kv0 + 63 > wq0);
#pragma unroll
      for (int nt = 0; nt < 4; nt++) {
        int kv = kv0 + nt * 16 + l15;
        int qr = wq0 + quad * 4;
#pragma unroll
        for (int r = 0; r < 4; r++) {
          float p = __builtin_exp2f(sacc[nt][r]);     // Q pre-scaled by log2e/8
          if (domask && kv > qr + r) p = 0.f;
          *(__bf16*)(pbp + ((pw[nt] ^ (r << 4)) + r * 128)) = (__bf16)p;
        }
      }

      // O += P V ; rsum += P * 1
#pragma unroll
      for (int ks = 0; ks < 2; ks++) {
        bf16x8 vf[4];
#pragma unroll
        for (int nt = 0; nt < 4; nt++)
          vf[nt] = *(const bf16x8*)(vbp + (kr[ks] + nt * 2048));
        bf16x8 pf = *(const bf16x8*)(pbp + pr[ks]);
        accs = MFMA16(pf, ones, accs);
#pragma unroll
        for (int nt = 0; nt < 4; nt++)
          acc[nt] = MFMA16(pf, vf[nt], acc[nt]);
      }
    }

    // epilogue: ones-acc rows (quad*4+r) match O-acc rows -> no shuffles
    __bf16* op = O + ((size_t)(b * S_LEN + wq0 + quad * 4)) * HID + h * HD;
    float inv[4];
#pragma unroll
    for (int r = 0; r < 4; r++) inv[r] = 1.f / accs[r];
#pragma unroll
    for (int nt = 0; nt < 4; nt++)
#pragma unroll
      for (int r = 0; r < 4; r++)
        op[(size_t)r * HID + nt * 16 + l15] = (__bf16)(acc[nt][r] * inv[r]);
  }
}

extern "C" void kernel_launch(void* const* d_in, const int* in_sizes, int n_in,
                              void* d_out, int out_size, void* d_ws, size_t ws_size,
                              hipStream_t stream) {
  (void)in_sizes; (void)n_in; (void)out_size; (void)ws_size;
  const float* x  = (const float*)d_in[0];
  const float* fr = (const float*)d_in[1];
  const float* wq = (const float*)d_in[3];
  const float* bq = (const float*)d_in[4];
  const float* wk = (const float*)d_in[5];
  const float* bk = (const float*)d_in[6];
  const float* wv = (const float*)d_in[7];
  const float* bv = (const float*)d_in[8];
  const float* wo = (const float*)d_in[9];
  const float* bo = (const float*)d_in[10];
  float* out = (float*)d_out;
  char* ws = (char*)d_ws;

  __bf16* xb  = (__bf16*)(ws);
  __bf16* wqb = (__bf16*)(ws + ((size_t)16 << 20));
  __bf16* wkb = (__bf16*)(ws + ((size_t)24 << 20));
  __bf16* wvb = (__bf16*)(ws + ((size_t)26 << 20));
  __bf16* wob = (__bf16*)(ws + ((size_t)28 << 20));
  __bf16* Qb  = (__bf16*)(ws + ((size_t)36 << 20));
  __bf16* Kb  = (__bf16*)(ws + ((size_t)52 << 20));
  __bf16* Vtb = (__bf16*)(ws + ((size_t)60 << 20));
  __bf16* Ab  = (__bf16*)(ws + ((size_t)64 << 20));

  cast_all_k<<<18432, 256, 0, stream>>>(x, wq, wk, wv, wo, xb, wqb, wkb, wvb, wob);

  gemm_qkv_k<<<dim3(16, 12), 512, 0, stream>>>(xb, wqb, wkb, wvb, bq, bk, bv, fr, Qb, Kb, Vtb);

  flash_k<<<dim3(64, 16), 256, 0, stream>>>(Qb, Kb, Vtb, Ab);

  gemm_out_k<<<dim3(16, 8), 512, 0, stream>>>(Ab, wob, bo, out);
}

// Round 3
// 347.300 us; speedup vs baseline: 1.0724x; 1.0724x over previous
//
#include <hip/hip_runtime.h>

#define S_LEN 2048
#define HID   2048
#define NQH   32
#define NKV   8
#define HD    64

#define BM 256
#define BN 256
#define BK 64
#define NTILES (HID / BK)   // 32

typedef __bf16 bf16x8 __attribute__((ext_vector_type(8)));
typedef __bf16 bf16x4 __attribute__((ext_vector_type(4)));
typedef float  f32x4  __attribute__((ext_vector_type(4)));

#define MFMA16(a, b, c) __builtin_amdgcn_mfma_f32_16x16x32_bf16(a, b, c, 0, 0, 0)

__device__ __forceinline__ void async_copy16(const void* g, void* l) {
  __builtin_amdgcn_global_load_lds(
      (const __attribute__((address_space(1))) unsigned int*)g,
      (__attribute__((address_space(3))) unsigned int*)l, 16, 0, 0);
}

#define FENCE asm volatile("" ::: "memory")
#define BARRIER do { FENCE; __builtin_amdgcn_s_barrier(); FENCE; } while (0)

// ---------------- fused f32 -> bf16 cast of x + all weights ----------------
__global__ void cast_all_k(const float* __restrict__ x,  const float* __restrict__ wq,
                           const float* __restrict__ wk, const float* __restrict__ wv,
                           const float* __restrict__ wo,
                           __bf16* __restrict__ xb,  __bf16* __restrict__ wqb,
                           __bf16* __restrict__ wkb, __bf16* __restrict__ wvb,
                           __bf16* __restrict__ wob) {
  int bid = blockIdx.x;
  const float* in; __bf16* out; int base;
  if (bid < 8192)       { in = x;  out = xb;  base = bid; }
  else if (bid < 12288) { in = wq; out = wqb; base = bid - 8192; }
  else if (bid < 13312) { in = wk; out = wkb; base = bid - 12288; }
  else if (bid < 14336) { in = wv; out = wvb; base = bid - 13312; }
  else                  { in = wo; out = wob; base = bid - 14336; }
  int i = (base * 256 + threadIdx.x) * 4;
  float4 v = *(const float4*)(in + i);
  bf16x4 o;
  o[0] = (__bf16)v.x; o[1] = (__bf16)v.y; o[2] = (__bf16)v.z; o[3] = (__bf16)v.w;
  *(bf16x4*)(out + i) = o;
}

// ---------------- 256x256 single-barrier pipelined GEMM core ----------------
// acc = A[M,K] * B[N,K]^T. 512 threads / 8 waves as 2(M)x4(N); per-wave 128x64.
// LDS: 2 x (256x64) per matrix = 128 KiB double-buffer, XOR-swizzled (T2).
// Per K-tile: stage t+1 (8 gload_lds, issued at TOP) -> 24 ds_read + 64 MFMA
// (compiler interleaves via fine lgkmcnt; NO intra-tile barriers so LDS pipe
// overlaps matrix pipe) -> vmcnt(0) with full-tile cover -> ONE barrier.
// Race-safety: a wave's ds_reads of buf s complete before its MFMAs (lgkm)
// and thus before its barrier arrival; staging into s resumes only after the
// NEXT barrier -> WAR safe. Buf s^1 certified by the barrier (all waves did
// vmcnt(0) before it).
__device__ __forceinline__ void gemm_pipe(const __bf16* __restrict__ A,
                                          const __bf16* __restrict__ B,
                                          int m0, int n0, int K,
                                          __bf16 (&As)[2][BM][BK],
                                          __bf16 (&Bs)[2][BN][BK],
                                          f32x4 (&acc)[8][4]) {
  const int tid = threadIdx.x, wave = tid >> 6, lane = tid & 63;
  const int l15 = lane & 15, quad = lane >> 4;
  const int wr = wave >> 2, wc = wave & 3;

  // staging map: rows wave*8 + lane>>3 (+64 per sweep), chunk lane&7;
  // global source column pre-swizzled by row&7 (T2, rule #21).
  const int srow8 = lane >> 3;
  const int scol  = ((lane & 7) ^ srow8) * 8;
  const __bf16* gA = A + (size_t)(m0 + wave * 8 + srow8) * K + scol;
  const __bf16* gB = B + (size_t)(n0 + wave * 8 + srow8) * K + scol;

  // ds_read chunk offsets: chunk = (kk*4+quad) ^ (row&7), row&7 == l15&7
  const int c0 = ((quad)     ^ (l15 & 7)) * 8;
  const int c1 = ((4 + quad) ^ (l15 & 7)) * 8;

#define STAGE8(sb, kt) do {                                                          \
    _Pragma("unroll")                                                                \
    for (int sw = 0; sw < 4; sw++)                                                   \
      async_copy16(gA + (kt) + (size_t)(sw * 64) * K, &As[sb][sw * 64 + wave * 8][0]); \
    _Pragma("unroll")                                                                \
    for (int sw = 0; sw < 4; sw++)                                                   \
      async_copy16(gB + (kt) + (size_t)(sw * 64) * K, &Bs[sb][sw * 64 + wave * 8][0]); \
  } while (0)

  STAGE8(0, 0);
  asm volatile("s_waitcnt vmcnt(0)" ::: "memory");
  BARRIER;

  int s = 0;
#pragma unroll 1
  for (int t = 0; t < NTILES; t++) {
    // issue next tile's loads first: they fly under this tile's compute
    if (t + 1 < NTILES) STAGE8(s ^ 1, (t + 1) * BK);

    const __bf16* a0 = &As[s][wr * 128][0];
    const __bf16* b0 = &Bs[s][wc * 64][0];

    bf16x8 bfr[4][2];
#pragma unroll
    for (int nt = 0; nt < 4; nt++) {
      bfr[nt][0] = *(const bf16x8*)(b0 + (nt * 16 + l15) * BK + c0);
      bfr[nt][1] = *(const bf16x8*)(b0 + (nt * 16 + l15) * BK + c1);
    }

    // ---- first 128-row half (mt 0..3) ----
    {
      bf16x8 af[4][2];
#pragma unroll
      for (int mt = 0; mt < 4; mt++) {
        af[mt][0] = *(const bf16x8*)(a0 + (mt * 16 + l15) * BK + c0);
        af[mt][1] = *(const bf16x8*)(a0 + (mt * 16 + l15) * BK + c1);
      }
      __builtin_amdgcn_s_setprio(1);
#pragma unroll
      for (int mt = 0; mt < 4; mt++)
#pragma unroll
        for (int nt = 0; nt < 4; nt++)
#pragma unroll
          for (int kk = 0; kk < 2; kk++)
            acc[mt][nt] = MFMA16(af[mt][kk], bfr[nt][kk], acc[mt][nt]);
      __builtin_amdgcn_s_setprio(0);
    }
    // ---- second 128-row half (mt 4..7) ----
    {
      bf16x8 ag[4][2];
#pragma unroll
      for (int mt = 0; mt < 4; mt++) {
        ag[mt][0] = *(const bf16x8*)(a0 + ((mt + 4) * 16 + l15) * BK + c0);
        ag[mt][1] = *(const bf16x8*)(a0 + ((mt + 4) * 16 + l15) * BK + c1);
      }
      __builtin_amdgcn_s_setprio(1);
#pragma unroll
      for (int mt = 0; mt < 4; mt++)
#pragma unroll
        for (int nt = 0; nt < 4; nt++)
#pragma unroll
          for (int kk = 0; kk < 2; kk++)
            acc[mt + 4][nt] = MFMA16(ag[mt][kk], bfr[nt][kk], acc[mt + 4][nt]);
      __builtin_amdgcn_s_setprio(0);
    }

    // staging for t+1 was issued a full tile (~2500 cyc) ago -> near-free wait
    asm volatile("s_waitcnt vmcnt(0)" ::: "memory");
    BARRIER;
    s ^= 1;
  }
#undef STAGE8
}

// fused QKV projection + RoPE(Q,K) + V transpose. grid (16, 12), 512 thr
__global__ __launch_bounds__(512, 2) void gemm_qkv_k(const __bf16* __restrict__ xb,
    const __bf16* __restrict__ wqb, const __bf16* __restrict__ wkb, const __bf16* __restrict__ wvb,
    const float* __restrict__ bq, const float* __restrict__ bk, const float* __restrict__ bv,
    const float* __restrict__ fr,
    __bf16* __restrict__ Qb, __bf16* __restrict__ Kb, __bf16* __restrict__ Vt) {
  __shared__ __align__(16) __bf16 As[2][BM][BK];
  __shared__ __align__(16) __bf16 Bs[2][BN][BK];
  const int by = blockIdx.y;
  const int m0 = blockIdx.x * BM;
  const __bf16* B; const float* bias; int n0;
  int mode;  // 0 = ropeQ, 1 = ropeK, 2 = vtrans
  if (by < 8)       { B = wqb; bias = bq; n0 = by * 256;        mode = 0; }
  else if (by < 10) { B = wkb; bias = bk; n0 = (by - 8) * 256;  mode = 1; }
  else              { B = wvb; bias = bv; n0 = (by - 10) * 256; mode = 2; }

  f32x4 acc[8][4] = {};
  gemm_pipe(xb, B, m0, n0, HID, As, Bs, acc);

  const int tid = threadIdx.x, wave = tid >> 6, lane = tid & 63;
  const int l15 = lane & 15, quad = lane >> 4;
  const int wr = wave >> 2, wc = wave & 3;

  if (mode == 2) {
#pragma unroll
    for (int nt = 0; nt < 4; nt++) {
      int col = n0 + wc * 64 + nt * 16 + l15;       // 0..511
      int g = col >> 6, d = col & 63;
      float bv2 = bias[col];
#pragma unroll
      for (int mt = 0; mt < 8; mt++) {
        int row = m0 + wr * 128 + mt * 16 + quad * 4;
        int b = row >> 11, sI = row & 2047;
        bf16x4 o;
#pragma unroll
        for (int r = 0; r < 4; r++) o[r] = (__bf16)(acc[mt][nt][r] + bv2);
        *(bf16x4*)(Vt + (((size_t)(b * NKV + g) * HD + d)) * S_LEN + sI) = o;
      }
    }
  } else {
    const float scale = (mode == 0) ? 0.125f * 1.44269504f : 1.0f;
    const int ldc = (mode == 0) ? HID : 512;
    __bf16* C = (mode == 0) ? Qb : Kb;
    const int dpar = l15 & 1;
#pragma unroll
    for (int nt = 0; nt < 4; nt++) {
      int col = n0 + wc * 64 + nt * 16 + l15;
      int d = col & 63;
      float bv2 = bias[col];
#pragma unroll
      for (int mt = 0; mt < 8; mt++) {
        int row = m0 + wr * 128 + mt * 16 + quad * 4;
        int sI = row & 2047;
#pragma unroll
        for (int r = 0; r < 4; r++) {
          float v = acc[mt][nt][r] + bv2;
          float p = __shfl_xor(v, 1, 64);
          float f = fr[(size_t)(sI + r) * HD + d];
          float fp = __shfl_xor(f, 1, 64);
          float o = dpar ? (p * f + v * fp) : (v * f - p * fp);
          C[(size_t)(row + r) * ldc + col] = (__bf16)(o * scale);
        }
      }
    }
  }
}

// output projection: grid (16, 8), 512 thr
__global__ __launch_bounds__(512, 2) void gemm_out_k(const __bf16* __restrict__ A,
    const __bf16* __restrict__ Bw, const float* __restrict__ bias, float* __restrict__ C) {
  __shared__ __align__(16) __bf16 As[2][BM][BK];
  __shared__ __align__(16) __bf16 Bs[2][BN][BK];
  const int m0 = blockIdx.x * BM, n0 = blockIdx.y * BN;
  f32x4 acc[8][4] = {};
  gemm_pipe(A, Bw, m0, n0, HID, As, Bs, acc);
  const int tid = threadIdx.x, wave = tid >> 6, lane = tid & 63;
  const int l15 = lane & 15, quad = lane >> 4;
  const int wr = wave >> 2, wc = wave & 3;
#pragma unroll
  for (int nt = 0; nt < 4; nt++) {
    int col = n0 + wc * 64 + nt * 16 + l15;
    float bv = bias[col];
#pragma unroll
    for (int mt = 0; mt < 8; mt++) {
      int row = m0 + wr * 128 + mt * 16 + quad * 4;
#pragma unroll
      for (int r = 0; r < 4; r++)
        C[(size_t)(row + r) * HID + col] = acc[mt][nt][r] + bv;
    }
  }
}

// ---------------- Flash attention v6: uniform-work blocks ----------------
// 64-row q-tiles (32 tiles). Block y processes the PAIR (qt=y, qt=31-y):
// kv-iters = (y+1)+(32-y) = 33 for EVERY block -> zero drain tail at 4 blocks/CU.
// 4 waves x 16 q-rows; no-max softmax (exp2, Q pre-scaled log2e/8); rsum via
// ones-MFMA; swizzled LDS, XOR-decomposed addresses.
__global__ __launch_bounds__(256, 4) void flash_k(const __bf16* __restrict__ Q,
                                                  const __bf16* __restrict__ K,
                                                  const __bf16* __restrict__ Vt,
                                                  __bf16* __restrict__ O) {
  __shared__ __align__(64) __bf16 Ksm[64][64];       // [kv][d] swizzled (key=row&7)
  __shared__ __align__(64) __bf16 Vsm[64][64];       // [d][kv] swizzled
  __shared__ __align__(64) __bf16 Psm[4][16][64];    // per-wave [q][kv] swizzled
  const int tid = threadIdx.x;
  const int wave = tid >> 6, lane = tid & 63;
  const int l15 = lane & 15, quad = lane >> 4;
  const int x7 = l15 & 7, l15h = l15 >> 3;
  const int bh = blockIdx.x;
  const int b = bh >> 5, h = bh & 31, g = h >> 2;

  const int srow = tid >> 2, sc = (tid & 3) * 16;
  const int r7 = srow & 7;
  const int w0 = (((sc >> 3))     ^ r7) * 8;
  const int w1 = (((sc >> 3) + 1) ^ r7) * 8;

  char* kbp = (char*)&Ksm[0][0];
  char* vbp = (char*)&Vsm[0][0];
  char* pbp = (char*)&Psm[0][0][0];
  int kr[2], pr[2], pw[4];
#pragma unroll
  for (int ks = 0; ks < 2; ks++) {
    kr[ks] = l15 * 128 + (((ks * 4 + quad) ^ x7) * 16);
    pr[ks] = wave * 2048 + kr[ks];
  }
#pragma unroll
  for (int nt = 0; nt < 4; nt++)
    pw[nt] = wave * 2048 + quad * 512 + x7 * 2 + (((2 * nt + l15h) ^ ((quad & 1) * 4)) * 16);

  bf16x8 ones;
#pragma unroll
  for (int j = 0; j < 8; j++) ones[j] = (__bf16)1.0f;

  const __bf16* kbase = K + ((size_t)b * S_LEN + srow) * (NKV * HD) + g * HD + sc;
  const __bf16* vbase = Vt + (((size_t)b * NKV + g) * HD + srow) * S_LEN + sc;

#pragma unroll 1
  for (int half = 0; half < 2; half++) {
    const int qt = half ? (31 - (int)blockIdx.y) : (int)blockIdx.y;
    const int wq0 = qt * 64 + wave * 16;

    const __bf16* qp = Q + ((size_t)(b * S_LEN + wq0 + l15)) * HID + h * HD + quad * 8;
    bf16x8 qf0 = *(const bf16x8*)qp;
    bf16x8 qf1 = *(const bf16x8*)(qp + 32);

    f32x4 acc[4] = {};
    f32x4 accs = {};

    const __bf16* kp = kbase;
    const __bf16* vp = vbase;
    uint4 k0 = *(const uint4*)kp, k1 = *(const uint4*)(kp + 8);
    uint4 v0 = *(const uint4*)vp, v1 = *(const uint4*)(vp + 8);

    for (int t = 0; t <= qt; t++) {
      const int kv0 = t * 64;
      __syncthreads();
      *(uint4*)&Ksm[srow][w0] = k0;
      *(uint4*)&Ksm[srow][w1] = k1;
      *(uint4*)&Vsm[srow][w0] = v0;
      *(uint4*)&Vsm[srow][w1] = v1;
      if (t < qt) {
        kp += 64 * NKV * HD;  vp += 64;
        k0 = *(const uint4*)kp; k1 = *(const uint4*)(kp + 8);
        v0 = *(const uint4*)vp; v1 = *(const uint4*)(vp + 8);
      }
      __syncthreads();

      if (kv0 > wq0 + 15) continue;   // fully masked for this wave

      bf16x8 kf[2][4];
#pragma unroll
      for (int ks = 0; ks < 2; ks++)
#pragma unroll
        for (int nt = 0; nt < 4; nt++)
          kf[ks][nt] = *(const bf16x8*)(kbp + (kr[ks] + nt * 2048));

      f32x4 sacc[4] = {};
#pragma unroll
      for (int nt = 0; nt < 4; nt++) {
        sacc[nt] = MFMA16(qf0, kf[0][nt], sacc[nt]);
        sacc[nt] = MFMA16(qf1, kf[1][nt], sacc[nt]);
      }
      const bool domask = (kv0 + 63 > wq0);
#pragma unroll
      for (int nt = 0; nt < 4; nt++) {
        int kv = kv0 + nt * 16 + l15;
        int qr = wq0 + quad * 4;
#pragma unroll
        for (int r = 0; r < 4; r++) {
          float p = __builtin_exp2f(sacc[nt][r]);     // Q pre-scaled by log2e/8
          if (domask && kv > qr + r) p = 0.f;
          *(__bf16*)(pbp + ((pw[nt] ^ (r << 4)) + r * 128)) = (__bf16)p;
        }
      }

      // O += P V ; rsum += P * 1
#pragma unroll
      for (int ks = 0; ks < 2; ks++) {
        bf16x8 vf[4];
#pragma unroll
        for (int nt = 0; nt < 4; nt++)
          vf[nt] = *(const bf16x8*)(vbp + (kr[ks] + nt * 2048));
        bf16x8 pf = *(const bf16x8*)(pbp + pr[ks]);
        accs = MFMA16(pf, ones, accs);
#pragma unroll
        for (int nt = 0; nt < 4; nt++)
          acc[nt] = MFMA16(pf, vf[nt], acc[nt]);
      }
    }

    // epilogue: ones-acc rows (quad*4+r) match O-acc rows -> no shuffles
    __bf16* op = O + ((size_t)(b * S_LEN + wq0 + quad * 4)) * HID + h * HD;
    float inv[4];
#pragma unroll
    for (int r = 0; r < 4; r++) inv[r] = 1.f / accs[r];
#pragma unroll
    for (int nt = 0; nt < 4; nt++)
#pragma unroll
      for (int r = 0; r < 4; r++)
        op[(size_t)r * HID + nt * 16 + l15] = (__bf16)(acc[nt][r] * inv[r]);
  }
}

extern "C" void kernel_launch(void* const* d_in, const int* in_sizes, int n_in,
                              void* d_out, int out_size, void* d_ws, size_t ws_size,
                              hipStream_t stream) {
  (void)in_sizes; (void)n_in; (void)out_size; (void)ws_size;
  const float* x  = (const float*)d_in[0];
  const float* fr = (const float*)d_in[1];
  const float* wq = (const float*)d_in[3];
  const float* bq = (const float*)d_in[4];
  const float* wk = (const float*)d_in[5];
  const float* bk = (const float*)d_in[6];
  const float* wv = (const float*)d_in[7];
  const float* bv = (const float*)d_in[8];
  const float* wo = (const float*)d_in[9];
  const float* bo = (const float*)d_in[10];
  float* out = (float*)d_out;
  char* ws = (char*)d_ws;

  __bf16* xb  = (__bf16*)(ws);
  __bf16* wqb = (__bf16*)(ws + ((size_t)16 << 20));
  __bf16* wkb = (__bf16*)(ws + ((size_t)24 << 20));
  __bf16* wvb = (__bf16*)(ws + ((size_t)26 << 20));
  __bf16* wob = (__bf16*)(ws + ((size_t)28 << 20));
  __bf16* Qb  = (__bf16*)(ws + ((size_t)36 << 20));
  __bf16* Kb  = (__bf16*)(ws + ((size_t)52 << 20));
  __bf16* Vtb = (__bf16*)(ws + ((size_t)60 << 20));
  __bf16* Ab  = (__bf16*)(ws + ((size_t)64 << 20));

  cast_all_k<<<18432, 256, 0, stream>>>(x, wq, wk, wv, wo, xb, wqb, wkb, wvb, wob);

  gemm_qkv_k<<<dim3(16, 12), 512, 0, stream>>>(xb, wqb, wkb, wvb, bq, bk, bv, fr, Qb, Kb, Vtb);

  flash_k<<<dim3(64, 16), 256, 0, stream>>>(Qb, Kb, Vtb, Ab);

  gemm_out_k<<<dim3(16, 8), 512, 0, stream>>>(Ab, wob, bo, out);
}

// Round 4
// 343.512 us; speedup vs baseline: 1.0842x; 1.0110x over previous
//
#include <hip/hip_runtime.h>

#define S_LEN 2048
#define HID   2048
#define NQH   32
#define NKV   8
#define HD    64

#define BM 256
#define BN 128
#define BK 64

typedef __bf16 bf16x8 __attribute__((ext_vector_type(8)));
typedef __bf16 bf16x4 __attribute__((ext_vector_type(4)));
typedef float  f32x4  __attribute__((ext_vector_type(4)));

#define MFMA16(a, b, c) __builtin_amdgcn_mfma_f32_16x16x32_bf16(a, b, c, 0, 0, 0)

__device__ __forceinline__ void async_copy16(const void* g, void* l) {
  __builtin_amdgcn_global_load_lds(
      (const __attribute__((address_space(1))) unsigned int*)g,
      (__attribute__((address_space(3))) unsigned int*)l, 16, 0, 0);
}

// ---------------- fused f32 -> bf16 cast of x + all weights ----------------
__global__ void cast_all_k(const float* __restrict__ x,  const float* __restrict__ wq,
                           const float* __restrict__ wk, const float* __restrict__ wv,
                           const float* __restrict__ wo,
                           __bf16* __restrict__ xb,  __bf16* __restrict__ wqb,
                           __bf16* __restrict__ wkb, __bf16* __restrict__ wvb,
                           __bf16* __restrict__ wob) {
  int bid = blockIdx.x;
  const float* in; __bf16* out; int base;
  if (bid < 8192)       { in = x;  out = xb;  base = bid; }
  else if (bid < 12288) { in = wq; out = wqb; base = bid - 8192; }
  else if (bid < 13312) { in = wk; out = wkb; base = bid - 12288; }
  else if (bid < 14336) { in = wv; out = wvb; base = bid - 13312; }
  else                  { in = wo; out = wob; base = bid - 14336; }
  int i = (base * 256 + threadIdx.x) * 4;
  float4 v = *(const float4*)(in + i);
  bf16x4 o;
  o[0] = (__bf16)v.x; o[1] = (__bf16)v.y; o[2] = (__bf16)v.z; o[3] = (__bf16)v.w;
  *(bf16x4*)(out + i) = o;
}

// ---------------- pipelined GEMM core: acc = A[M,K] * B[N,K]^T (R1, best) ----------------
// BM=256 BN=128 BK=64, 512 threads (8 waves, 4x2), 3-stage LDS (144 KiB),
// depth-2 prefetch, counted s_waitcnt vmcnt(6) (never 0 in steady state),
// ONE raw s_barrier per K-tile, XOR-swizzled LDS (T2), setprio around MFMA (T5).
__device__ __forceinline__ void gemm_pipe(const __bf16* __restrict__ A,
                                          const __bf16* __restrict__ B,
                                          int m0, int n0, int K,
                                          __bf16 (&As)[3][BM][BK],
                                          __bf16 (&Bs)[3][BN][BK],
                                          f32x4 (&acc)[4][4]) {
  const int tid = threadIdx.x, wave = tid >> 6, lane = tid & 63;
  const int l15 = lane & 15, quad = lane >> 4;
  const int wr = wave >> 1, wc = wave & 1;

  // staging: one gload_lds writes 1 KiB = 8 rows x 128 B (linear dest).
  // source column pre-swizzled by (row&7) so a swizzled ds_read recovers it.
  const int srow = lane >> 3;                       // 0..7 within 8-row group
  const int scol = ((lane & 7) ^ srow) * 8;         // swizzled col (elems)
  const __bf16* ga = A + (size_t)(m0 + wave * 32 + srow) * K + scol;
  const __bf16* gb = B + (size_t)(n0 + wave * 16 + srow) * K + scol;

  // ds_read chunk offsets (bytes/2 = elems), chunk = (kk*4+quad) ^ (row&7)
  const int c0 = ((quad)     ^ (l15 & 7)) * 8;
  const int c1 = ((4 + quad) ^ (l15 & 7)) * 8;

  const int NT = K / BK;  // 32

#define STAGE(st, kt) do {                                                        \
    _Pragma("unroll")                                                             \
    for (int i = 0; i < 4; i++)                                                   \
      async_copy16(ga + (kt) + (size_t)(i * 8) * K, &As[st][wave * 32 + i * 8][0]); \
    _Pragma("unroll")                                                             \
    for (int i = 0; i < 2; i++)                                                   \
      async_copy16(gb + (kt) + (size_t)(i * 8) * K, &Bs[st][wave * 16 + i * 8][0]); \
  } while (0)

  STAGE(0, 0);
  STAGE(1, BK);

  int s = 0;
  for (int t = 0; t < NT; t++) {
    // lgkmcnt(0): my previous tile's ds_reads complete before I pass the
    // barrier (next stage overwrites that buffer). vmcnt(6): wait only for
    // tile t's 6 loads; tile t+1's 6 stay in flight across the barrier.
    if (t + 1 < NT) asm volatile("s_waitcnt vmcnt(6) lgkmcnt(0)" ::: "memory");
    else            asm volatile("s_waitcnt vmcnt(0) lgkmcnt(0)" ::: "memory");
    __builtin_amdgcn_s_barrier();
    asm volatile("" ::: "memory");

    if (t + 2 < NT) {
      int s2 = s + 2; if (s2 >= 3) s2 -= 3;
      STAGE(s2, (t + 2) * BK);
    }

    const __bf16* a0 = &As[s][wr * 64][0];
    const __bf16* b0 = &Bs[s][wc * 64][0];
    bf16x8 af[2][4], bfr[2][4];
#pragma unroll
    for (int mt = 0; mt < 4; mt++) {
      af[0][mt] = *(const bf16x8*)(a0 + (mt * 16 + l15) * BK + c0);
      af[1][mt] = *(const bf16x8*)(a0 + (mt * 16 + l15) * BK + c1);
    }
#pragma unroll
    for (int nt = 0; nt < 4; nt++) {
      bfr[0][nt] = *(const bf16x8*)(b0 + (nt * 16 + l15) * BK + c0);
      bfr[1][nt] = *(const bf16x8*)(b0 + (nt * 16 + l15) * BK + c1);
    }

    __builtin_amdgcn_s_setprio(1);
#pragma unroll
    for (int kk = 0; kk < 2; kk++)
#pragma unroll
      for (int mt = 0; mt < 4; mt++)
#pragma unroll
        for (int nt = 0; nt < 4; nt++)
          acc[mt][nt] = MFMA16(af[kk][mt], bfr[kk][nt], acc[mt][nt]);
    __builtin_amdgcn_s_setprio(0);

    s = s + 1; if (s >= 3) s -= 3;
  }
#undef STAGE
}

// fused QKV projection + RoPE(K) + V transpose. grid (16, 24), 512 thr.
// Q is written RAW (bias only) -- RoPE+scale applied in flash_k where the
// pair elements are register-adjacent and fr loads are contiguous.
__global__ __launch_bounds__(512, 2) void gemm_qkv_k(const __bf16* __restrict__ xb,
    const __bf16* __restrict__ wqb, const __bf16* __restrict__ wkb, const __bf16* __restrict__ wvb,
    const float* __restrict__ bq, const float* __restrict__ bk, const float* __restrict__ bv,
    const float* __restrict__ fr,
    __bf16* __restrict__ Qb, __bf16* __restrict__ Kb, __bf16* __restrict__ Vt) {
  __shared__ __align__(16) __bf16 As[3][BM][BK];
  __shared__ __align__(16) __bf16 Bs[3][BN][BK];
  const int by = blockIdx.y;
  const int m0 = blockIdx.x * BM;
  const __bf16* B; const float* bias; int n0;
  int mode;  // 0 = plain Q, 1 = ropeK, 2 = vtrans
  if (by < 16)      { B = wqb; bias = bq; n0 = by * 128;        mode = 0; }
  else if (by < 20) { B = wkb; bias = bk; n0 = (by - 16) * 128; mode = 1; }
  else              { B = wvb; bias = bv; n0 = (by - 20) * 128; mode = 2; }

  f32x4 acc[4][4] = {};
  gemm_pipe(xb, B, m0, n0, HID, As, Bs, acc);

  const int tid = threadIdx.x, wave = tid >> 6, lane = tid & 63;
  const int l15 = lane & 15, quad = lane >> 4;
  const int wr = wave >> 1, wc = wave & 1;

  if (mode == 2) {
#pragma unroll
    for (int nt = 0; nt < 4; nt++) {
      int col = n0 + wc * 64 + nt * 16 + l15;       // 0..511
      int g = col >> 6, d = col & 63;
      float bv2 = bias[col];
#pragma unroll
      for (int mt = 0; mt < 4; mt++) {
        int row = m0 + wr * 64 + mt * 16 + quad * 4;
        int b = row >> 11, sI = row & 2047;
        bf16x4 o;
#pragma unroll
        for (int r = 0; r < 4; r++) o[r] = (__bf16)(acc[mt][nt][r] + bv2);
        *(bf16x4*)(Vt + (((size_t)(b * NKV + g) * HD + d)) * S_LEN + sI) = o;
      }
    }
  } else if (mode == 0) {
    // plain bias + store (RoPE moved to flash_k)
#pragma unroll
    for (int nt = 0; nt < 4; nt++) {
      int col = n0 + wc * 64 + nt * 16 + l15;
      float bv2 = bias[col];
#pragma unroll
      for (int mt = 0; mt < 4; mt++) {
        int row = m0 + wr * 64 + mt * 16 + quad * 4;
#pragma unroll
        for (int r = 0; r < 4; r++)
          Qb[(size_t)(row + r) * HID + col] = (__bf16)(acc[mt][nt][r] + bv2);
      }
    }
  } else {
    const int dpar = l15 & 1;
#pragma unroll
    for (int nt = 0; nt < 4; nt++) {
      int col = n0 + wc * 64 + nt * 16 + l15;
      int d = col & 63;
      float bv2 = bias[col];
#pragma unroll
      for (int mt = 0; mt < 4; mt++) {
        int row = m0 + wr * 64 + mt * 16 + quad * 4;
        int sI = row & 2047;
#pragma unroll
        for (int r = 0; r < 4; r++) {
          float v = acc[mt][nt][r] + bv2;
          float p = __shfl_xor(v, 1, 64);
          float f = fr[(size_t)(sI + r) * HD + d];
          float fp = __shfl_xor(f, 1, 64);
          float o = dpar ? (p * f + v * fp) : (v * f - p * fp);
          Kb[(size_t)(row + r) * 512 + col] = (__bf16)o;
        }
      }
    }
  }
}

// output projection: grid (16, 16), 512 thr -- exactly 1 block/CU
__global__ __launch_bounds__(512, 2) void gemm_out_k(const __bf16* __restrict__ A,
    const __bf16* __restrict__ Bw, const float* __restrict__ bias, float* __restrict__ C) {
  __shared__ __align__(16) __bf16 As[3][BM][BK];
  __shared__ __align__(16) __bf16 Bs[3][BN][BK];
  const int m0 = blockIdx.x * BM, n0 = blockIdx.y * BN;
  f32x4 acc[4][4] = {};
  gemm_pipe(A, Bw, m0, n0, HID, As, Bs, acc);
  const int tid = threadIdx.x, wave = tid >> 6, lane = tid & 63;
  const int l15 = lane & 15, quad = lane >> 4;
  const int wr = wave >> 1, wc = wave & 1;
#pragma unroll
  for (int nt = 0; nt < 4; nt++) {
    int col = n0 + wc * 64 + nt * 16 + l15;
    float bv = bias[col];
#pragma unroll
    for (int mt = 0; mt < 4; mt++) {
      int row = m0 + wr * 64 + mt * 16 + quad * 4;
#pragma unroll
      for (int r = 0; r < 4; r++)
        C[(size_t)(row + r) * HID + col] = acc[mt][nt][r] + bv;
    }
  }
}

// RoPE a bf16x8 (pairs 2j,2j+1 adjacent) with contiguous f32 freqs, fused scale.
__device__ __forceinline__ void rope8(bf16x8& q, const float* f, float sc) {
  float4 fa = *(const float4*)f;
  float4 fb = *(const float4*)(f + 4);
  float e, o;
  e = (float)q[0]; o = (float)q[1];
  q[0] = (__bf16)((e * fa.x - o * fa.y) * sc);
  q[1] = (__bf16)((e * fa.y + o * fa.x) * sc);
  e = (float)q[2]; o = (float)q[3];
  q[2] = (__bf16)((e * fa.z - o * fa.w) * sc);
  q[3] = (__bf16)((e * fa.w + o * fa.z) * sc);
  e = (float)q[4]; o = (float)q[5];
  q[4] = (__bf16)((e * fb.x - o * fb.y) * sc);
  q[5] = (__bf16)((e * fb.y + o * fb.x) * sc);
  e = (float)q[6]; o = (float)q[7];
  q[6] = (__bf16)((e * fb.z - o * fb.w) * sc);
  q[7] = (__bf16)((e * fb.w + o * fb.z) * sc);
}

// ---------------- Flash attention v7: uniform-work blocks, in-reg Q-RoPE ----------------
// 64-row q-tiles (32 tiles). Block y processes the PAIR (qt=y, qt=31-y):
// kv-iters = (y+1)+(32-y) = 33 for EVERY block -> zero drain tail at 4 blocks/CU.
// 4 waves x 16 q-rows; no-max softmax (exp2; Q RoPE'd+scaled in-register here,
// pairs are register-adjacent so no shuffles); rsum via ones-MFMA; swizzled LDS.
__global__ __launch_bounds__(256, 4) void flash_k(const __bf16* __restrict__ Q,
                                                  const __bf16* __restrict__ K,
                                                  const __bf16* __restrict__ Vt,
                                                  const float* __restrict__ fr,
                                                  __bf16* __restrict__ O) {
  __shared__ __align__(64) __bf16 Ksm[64][64];       // [kv][d] swizzled (key=row&7)
  __shared__ __align__(64) __bf16 Vsm[64][64];       // [d][kv] swizzled
  __shared__ __align__(64) __bf16 Psm[4][16][64];    // per-wave [q][kv] swizzled
  const int tid = threadIdx.x;
  const int wave = tid >> 6, lane = tid & 63;
  const int l15 = lane & 15, quad = lane >> 4;
  const int x7 = l15 & 7, l15h = l15 >> 3;
  const int bh = blockIdx.x;
  const int b = bh >> 5, h = bh & 31, g = h >> 2;

  const int srow = tid >> 2, sc = (tid & 3) * 16;
  const int r7 = srow & 7;
  const int w0 = (((sc >> 3))     ^ r7) * 8;
  const int w1 = (((sc >> 3) + 1) ^ r7) * 8;

  char* kbp = (char*)&Ksm[0][0];
  char* vbp = (char*)&Vsm[0][0];
  char* pbp = (char*)&Psm[0][0][0];
  int kr[2], pr[2], pw[4];
#pragma unroll
  for (int ks = 0; ks < 2; ks++) {
    kr[ks] = l15 * 128 + (((ks * 4 + quad) ^ x7) * 16);
    pr[ks] = wave * 2048 + kr[ks];
  }
#pragma unroll
  for (int nt = 0; nt < 4; nt++)
    pw[nt] = wave * 2048 + quad * 512 + x7 * 2 + (((2 * nt + l15h) ^ ((quad & 1) * 4)) * 16);

  bf16x8 ones;
#pragma unroll
  for (int j = 0; j < 8; j++) ones[j] = (__bf16)1.0f;

  const __bf16* kbase = K + ((size_t)b * S_LEN + srow) * (NKV * HD) + g * HD + sc;
  const __bf16* vbase = Vt + (((size_t)b * NKV + g) * HD + srow) * S_LEN + sc;
  const float QSC = 0.125f * 1.44269504f;   // 1/sqrt(64) * log2(e)

#pragma unroll 1
  for (int half = 0; half < 2; half++) {
    const int qt = half ? (31 - (int)blockIdx.y) : (int)blockIdx.y;
    const int wq0 = qt * 64 + wave * 16;

    const __bf16* qp = Q + ((size_t)(b * S_LEN + wq0 + l15)) * HID + h * HD + quad * 8;
    bf16x8 qf0 = *(const bf16x8*)qp;
    bf16x8 qf1 = *(const bf16x8*)(qp + 32);
    // in-register RoPE + softmax scale (pairs 2j,2j+1 adjacent; fr contiguous)
    const float* fq = fr + (size_t)(wq0 + l15) * HD + quad * 8;
    rope8(qf0, fq, QSC);
    rope8(qf1, fq + 32, QSC);

    f32x4 acc[4] = {};
    f32x4 accs = {};

    const __bf16* kp = kbase;
    const __bf16* vp = vbase;
    uint4 k0 = *(const uint4*)kp, k1 = *(const uint4*)(kp + 8);
    uint4 v0 = *(const uint4*)vp, v1 = *(const uint4*)(vp + 8);

    for (int t = 0; t <= qt; t++) {
      const int kv0 = t * 64;
      __syncthreads();
      *(uint4*)&Ksm[srow][w0] = k0;
      *(uint4*)&Ksm[srow][w1] = k1;
      *(uint4*)&Vsm[srow][w0] = v0;
      *(uint4*)&Vsm[srow][w1] = v1;
      if (t < qt) {
        kp += 64 * NKV * HD;  vp += 64;
        k0 = *(const uint4*)kp; k1 = *(const uint4*)(kp + 8);
        v0 = *(const uint4*)vp; v1 = *(const uint4*)(vp + 8);
      }
      __syncthreads();

      if (kv0 > wq0 + 15) continue;   // fully masked for this wave

      bf16x8 kf[2][4];
#pragma unroll
      for (int ks = 0; ks < 2; ks++)
#pragma unroll
        for (int nt = 0; nt < 4; nt++)
          kf[ks][nt] = *(const bf16x8*)(kbp + (kr[ks] + nt * 2048));

      f32x4 sacc[4] = {};
#pragma unroll
      for (int nt = 0; nt < 4; nt++) {
        sacc[nt] = MFMA16(qf0, kf[0][nt], sacc[nt]);
        sacc[nt] = MFMA16(qf1, kf[1][nt], sacc[nt]);
      }
      const bool domask = (kv0 + 63 > wq0);
#pragma unroll
      for (int nt = 0; nt < 4; nt++) {
        int kv = kv0 + nt * 16 + l15;
        int qr = wq0 + quad * 4;
#pragma unroll
        for (int r = 0; r < 4; r++) {
          float p = __builtin_exp2f(sacc[nt][r]);     // Q pre-scaled by log2e/8
          if (domask && kv > qr + r) p = 0.f;
          *(__bf16*)(pbp + ((pw[nt] ^ (r << 4)) + r * 128)) = (__bf16)p;
        }
      }

      // O += P V ; rsum += P * 1
#pragma unroll
      for (int ks = 0; ks < 2; ks++) {
        bf16x8 vf[4];
#pragma unroll
        for (int nt = 0; nt < 4; nt++)
          vf[nt] = *(const bf16x8*)(vbp + (kr[ks] + nt * 2048));
        bf16x8 pf = *(const bf16x8*)(pbp + pr[ks]);
        accs = MFMA16(pf, ones, accs);
#pragma unroll
        for (int nt = 0; nt < 4; nt++)
          acc[nt] = MFMA16(pf, vf[nt], acc[nt]);
      }
    }

    // epilogue: ones-acc rows (quad*4+r) match O-acc rows -> no shuffles
    __bf16* op = O + ((size_t)(b * S_LEN + wq0 + quad * 4)) * HID + h * HD;
    float inv[4];
#pragma unroll
    for (int r = 0; r < 4; r++) inv[r] = 1.f / accs[r];
#pragma unroll
    for (int nt = 0; nt < 4; nt++)
#pragma unroll
      for (int r = 0; r < 4; r++)
        op[(size_t)r * HID + nt * 16 + l15] = (__bf16)(acc[nt][r] * inv[r]);
  }
}

extern "C" void kernel_launch(void* const* d_in, const int* in_sizes, int n_in,
                              void* d_out, int out_size, void* d_ws, size_t ws_size,
                              hipStream_t stream) {
  (void)in_sizes; (void)n_in; (void)out_size; (void)ws_size;
  const float* x  = (const float*)d_in[0];
  const float* fr = (const float*)d_in[1];
  const float* wq = (const float*)d_in[3];
  const float* bq = (const float*)d_in[4];
  const float* wk = (const float*)d_in[5];
  const float* bk = (const float*)d_in[6];
  const float* wv = (const float*)d_in[7];
  const float* bv = (const float*)d_in[8];
  const float* wo = (const float*)d_in[9];
  const float* bo = (const float*)d_in[10];
  float* out = (float*)d_out;
  char* ws = (char*)d_ws;

  __bf16* xb  = (__bf16*)(ws);
  __bf16* wqb = (__bf16*)(ws + ((size_t)16 << 20));
  __bf16* wkb = (__bf16*)(ws + ((size_t)24 << 20));
  __bf16* wvb = (__bf16*)(ws + ((size_t)26 << 20));
  __bf16* wob = (__bf16*)(ws + ((size_t)28 << 20));
  __bf16* Qb  = (__bf16*)(ws + ((size_t)36 << 20));
  __bf16* Kb  = (__bf16*)(ws + ((size_t)52 << 20));
  __bf16* Vtb = (__bf16*)(ws + ((size_t)60 << 20));
  __bf16* Ab  = (__bf16*)(ws + ((size_t)64 << 20));

  cast_all_k<<<18432, 256, 0, stream>>>(x, wq, wk, wv, wo, xb, wqb, wkb, wvb, wob);

  gemm_qkv_k<<<dim3(16, 24), 512, 0, stream>>>(xb, wqb, wkb, wvb, bq, bk, bv, fr, Qb, Kb, Vtb);

  flash_k<<<dim3(64, 16), 256, 0, stream>>>(Qb, Kb, Vtb, fr, Ab);

  gemm_out_k<<<dim3(16, 16), 512, 0, stream>>>(Ab, wob, bo, out);
}

// Round 5
// 315.208 us; speedup vs baseline: 1.1816x; 1.0898x over previous
//
#include <hip/hip_runtime.h>

#define S_LEN 2048
#define HID   2048
#define NQH   32
#define NKV   8
#define HD    64

#define BM 128
#define BN 128
#define BK 32

typedef __bf16 bf16x8 __attribute__((ext_vector_type(8)));
typedef __bf16 bf16x4 __attribute__((ext_vector_type(4)));
typedef float  f32x4  __attribute__((ext_vector_type(4)));

#define MFMA16(a, b, c) __builtin_amdgcn_mfma_f32_16x16x32_bf16(a, b, c, 0, 0, 0)

__device__ __forceinline__ void async_copy16(const void* g, void* l) {
  __builtin_amdgcn_global_load_lds(
      (const __attribute__((address_space(1))) unsigned int*)g,
      (__attribute__((address_space(3))) unsigned int*)l, 16, 0, 0);
}

// ---------------- fused f32 -> bf16 cast of x + all weights ----------------
__global__ void cast_all_k(const float* __restrict__ x,  const float* __restrict__ wq,
                           const float* __restrict__ wk, const float* __restrict__ wv,
                           const float* __restrict__ wo,
                           __bf16* __restrict__ xb,  __bf16* __restrict__ wqb,
                           __bf16* __restrict__ wkb, __bf16* __restrict__ wvb,
                           __bf16* __restrict__ wob) {
  int bid = blockIdx.x;
  const float* in; __bf16* out; int base;
  if (bid < 8192)       { in = x;  out = xb;  base = bid; }
  else if (bid < 12288) { in = wq; out = wqb; base = bid - 8192; }
  else if (bid < 13312) { in = wk; out = wkb; base = bid - 12288; }
  else if (bid < 14336) { in = wv; out = wvb; base = bid - 13312; }
  else                  { in = wo; out = wob; base = bid - 14336; }
  int i = (base * 256 + threadIdx.x) * 4;
  float4 v = *(const float4*)(in + i);
  bf16x4 o;
  o[0] = (__bf16)v.x; o[1] = (__bf16)v.y; o[2] = (__bf16)v.z; o[3] = (__bf16)v.w;
  *(bf16x4*)(out + i) = o;
}

// ---------------- 128x128 BK=32 co-resident GEMM core (m97-class) ----------------
// acc = A[M,K] * B[N,K]^T. 256 threads / 4 waves as 2x2; per-wave 64x64.
// LDS: 2-stage double buffer, 32 KiB total -> 4 blocks/CU co-resident; barrier
// stalls destagger across blocks (m114). One barrier per K-tile: stage t+1 at
// top (buffer certified free by previous barrier), 8 ds_read + 16 MFMA,
// vmcnt(0)+lgkmcnt(0) at bottom (lgkm guards WAR on restaged buffer).
// T2 swizzle for BK=32: chunk key k(row)=(row>>1)&3 -> <=2-way bank alias
// (free, m136). gload_lds dest is wave-uniform linear (wave covers rows
// w*16 + lane>>2, chunk lane&3); SOURCE column pre-XOR'd (rule #21).
__device__ __forceinline__ void gemm_pipe(const __bf16* __restrict__ A,
                                          const __bf16* __restrict__ B,
                                          int m0, int n0, int K,
                                          __bf16 (&As)[2][BM][BK],
                                          __bf16 (&Bs)[2][BN][BK],
                                          f32x4 (&acc)[4][4]) {
  const int tid = threadIdx.x, wave = tid >> 6, lane = tid & 63;
  const int l15 = lane & 15, quad = lane >> 4;
  const int wr = wave >> 1, wc = wave & 1;

  // staging: thread -> row tid>>2 (0..63; +64 sweep 1), dest chunk tid&3.
  // source chunk = dest ^ k(row), k(row) = (row>>1)&3 = (tid>>3)&3.
  const int srow   = tid >> 2;
  const int schunk = (tid & 3) ^ ((tid >> 3) & 3);
  const __bf16* ga = A + (size_t)(m0 + srow) * K + schunk * 8;
  const __bf16* gb = B + (size_t)(n0 + srow) * K + schunk * 8;

  // ds_read chunk offset (elems): quad ^ k, k = (l15>>1)&3 (row-bits 16/64 are 0 mod 4)
  const int co = (quad ^ ((l15 >> 1) & 3)) * 8;

  const int NT = K / BK;

#define STAGE(st, kt) do {                                              \
    async_copy16(ga + (kt),                  &As[st][wave * 16][0]);    \
    async_copy16(ga + (kt) + (size_t)64 * K, &As[st][64 + wave * 16][0]); \
    async_copy16(gb + (kt),                  &Bs[st][wave * 16][0]);    \
    async_copy16(gb + (kt) + (size_t)64 * K, &Bs[st][64 + wave * 16][0]); \
  } while (0)

  STAGE(0, 0);
  asm volatile("s_waitcnt vmcnt(0)" ::: "memory");
  __builtin_amdgcn_s_barrier();
  asm volatile("" ::: "memory");

  int s = 0;
#pragma unroll 2
  for (int t = 0; t < NT; t++) {
    // stage t+1 into the buffer freed by the previous barrier
    if (t + 1 < NT) STAGE(s ^ 1, (t + 1) * BK);

    const __bf16* a0 = &As[s][wr * 64][0];
    const __bf16* b0 = &Bs[s][wc * 64][0];
    bf16x8 af[4], bfr[4];
#pragma unroll
    for (int mt = 0; mt < 4; mt++)
      af[mt] = *(const bf16x8*)(a0 + (mt * 16 + l15) * BK + co);
#pragma unroll
    for (int nt = 0; nt < 4; nt++)
      bfr[nt] = *(const bf16x8*)(b0 + (nt * 16 + l15) * BK + co);

    __builtin_amdgcn_s_setprio(1);
#pragma unroll
    for (int mt = 0; mt < 4; mt++)
#pragma unroll
      for (int nt = 0; nt < 4; nt++)
        acc[mt][nt] = MFMA16(af[mt], bfr[nt], acc[mt][nt]);
    __builtin_amdgcn_s_setprio(0);

    // vmcnt: stage(t+1) landed; lgkm: my reads of buf s retired (WAR vs restage)
    asm volatile("s_waitcnt vmcnt(0) lgkmcnt(0)" ::: "memory");
    __builtin_amdgcn_s_barrier();
    asm volatile("" ::: "memory");
    s ^= 1;
  }
#undef STAGE
}

// fused QKV projection + RoPE(K) + V transpose. grid (32, 24), 256 thr.
// Q written raw (bias only) -- RoPE+scale applied in flash_k.
__global__ __launch_bounds__(256, 4) void gemm_qkv_k(const __bf16* __restrict__ xb,
    const __bf16* __restrict__ wqb, const __bf16* __restrict__ wkb, const __bf16* __restrict__ wvb,
    const float* __restrict__ bq, const float* __restrict__ bk, const float* __restrict__ bv,
    const float* __restrict__ fr,
    __bf16* __restrict__ Qb, __bf16* __restrict__ Kb, __bf16* __restrict__ Vt) {
  __shared__ __align__(16) __bf16 As[2][BM][BK];
  __shared__ __align__(16) __bf16 Bs[2][BN][BK];
  const int by = blockIdx.y;
  const int m0 = blockIdx.x * BM;
  const __bf16* B; const float* bias; int n0;
  int mode;  // 0 = plain Q, 1 = ropeK, 2 = vtrans
  if (by < 16)      { B = wqb; bias = bq; n0 = by * 128;        mode = 0; }
  else if (by < 20) { B = wkb; bias = bk; n0 = (by - 16) * 128; mode = 1; }
  else              { B = wvb; bias = bv; n0 = (by - 20) * 128; mode = 2; }

  f32x4 acc[4][4] = {};
  gemm_pipe(xb, B, m0, n0, HID, As, Bs, acc);

  const int tid = threadIdx.x, wave = tid >> 6, lane = tid & 63;
  const int l15 = lane & 15, quad = lane >> 4;
  const int wr = wave >> 1, wc = wave & 1;

  if (mode == 2) {
#pragma unroll
    for (int nt = 0; nt < 4; nt++) {
      int col = n0 + wc * 64 + nt * 16 + l15;       // 0..511
      int g = col >> 6, d = col & 63;
      float bv2 = bias[col];
#pragma unroll
      for (int mt = 0; mt < 4; mt++) {
        int row = m0 + wr * 64 + mt * 16 + quad * 4;
        int b = row >> 11, sI = row & 2047;
        bf16x4 o;
#pragma unroll
        for (int r = 0; r < 4; r++) o[r] = (__bf16)(acc[mt][nt][r] + bv2);
        *(bf16x4*)(Vt + (((size_t)(b * NKV + g) * HD + d)) * S_LEN + sI) = o;
      }
    }
  } else if (mode == 0) {
    // plain bias + store (RoPE moved to flash_k)
#pragma unroll
    for (int nt = 0; nt < 4; nt++) {
      int col = n0 + wc * 64 + nt * 16 + l15;
      float bv2 = bias[col];
#pragma unroll
      for (int mt = 0; mt < 4; mt++) {
        int row = m0 + wr * 64 + mt * 16 + quad * 4;
#pragma unroll
        for (int r = 0; r < 4; r++)
          Qb[(size_t)(row + r) * HID + col] = (__bf16)(acc[mt][nt][r] + bv2);
      }
    }
  } else {
    const int dpar = l15 & 1;
#pragma unroll
    for (int nt = 0; nt < 4; nt++) {
      int col = n0 + wc * 64 + nt * 16 + l15;
      int d = col & 63;
      float bv2 = bias[col];
#pragma unroll
      for (int mt = 0; mt < 4; mt++) {
        int row = m0 + wr * 64 + mt * 16 + quad * 4;
        int sI = row & 2047;
#pragma unroll
        for (int r = 0; r < 4; r++) {
          float v = acc[mt][nt][r] + bv2;
          float p = __shfl_xor(v, 1, 64);
          float f = fr[(size_t)(sI + r) * HD + d];
          float fp = __shfl_xor(f, 1, 64);
          float o = dpar ? (p * f + v * fp) : (v * f - p * fp);
          Kb[(size_t)(row + r) * 512 + col] = (__bf16)o;
        }
      }
    }
  }
}

// output projection: grid (32, 16) = 512 blocks -- exactly 2 blocks/CU
__global__ __launch_bounds__(256, 4) void gemm_out_k(const __bf16* __restrict__ A,
    const __bf16* __restrict__ Bw, const float* __restrict__ bias, float* __restrict__ C) {
  __shared__ __align__(16) __bf16 As[2][BM][BK];
  __shared__ __align__(16) __bf16 Bs[2][BN][BK];
  const int m0 = blockIdx.x * BM, n0 = blockIdx.y * BN;
  f32x4 acc[4][4] = {};
  gemm_pipe(A, Bw, m0, n0, HID, As, Bs, acc);
  const int tid = threadIdx.x, wave = tid >> 6, lane = tid & 63;
  const int l15 = lane & 15, quad = lane >> 4;
  const int wr = wave >> 1, wc = wave & 1;
#pragma unroll
  for (int nt = 0; nt < 4; nt++) {
    int col = n0 + wc * 64 + nt * 16 + l15;
    float bv = bias[col];
#pragma unroll
    for (int mt = 0; mt < 4; mt++) {
      int row = m0 + wr * 64 + mt * 16 + quad * 4;
#pragma unroll
      for (int r = 0; r < 4; r++)
        C[(size_t)(row + r) * HID + col] = acc[mt][nt][r] + bv;
    }
  }
}

// RoPE a bf16x8 (pairs 2j,2j+1 adjacent) with contiguous f32 freqs, fused scale.
__device__ __forceinline__ void rope8(bf16x8& q, const float* f, float sc) {
  float4 fa = *(const float4*)f;
  float4 fb = *(const float4*)(f + 4);
  float e, o;
  e = (float)q[0]; o = (float)q[1];
  q[0] = (__bf16)((e * fa.x - o * fa.y) * sc);
  q[1] = (__bf16)((e * fa.y + o * fa.x) * sc);
  e = (float)q[2]; o = (float)q[3];
  q[2] = (__bf16)((e * fa.z - o * fa.w) * sc);
  q[3] = (__bf16)((e * fa.w + o * fa.z) * sc);
  e = (float)q[4]; o = (float)q[5];
  q[4] = (__bf16)((e * fb.x - o * fb.y) * sc);
  q[5] = (__bf16)((e * fb.y + o * fb.x) * sc);
  e = (float)q[6]; o = (float)q[7];
  q[6] = (__bf16)((e * fb.z - o * fb.w) * sc);
  q[7] = (__bf16)((e * fb.w + o * fb.z) * sc);
}

// ---------------- Flash attention v7: uniform-work blocks, in-reg Q-RoPE ----------------
// 64-row q-tiles (32 tiles). Block y processes the PAIR (qt=y, qt=31-y):
// kv-iters = (y+1)+(32-y) = 33 for EVERY block -> zero drain tail at 4 blocks/CU.
// 4 waves x 16 q-rows; no-max softmax (exp2; Q RoPE'd+scaled in-register here,
// pairs are register-adjacent so no shuffles); rsum via ones-MFMA; swizzled LDS.
__global__ __launch_bounds__(256, 4) void flash_k(const __bf16* __restrict__ Q,
                                                  const __bf16* __restrict__ K,
                                                  const __bf16* __restrict__ Vt,
                                                  const float* __restrict__ fr,
                                                  __bf16* __restrict__ O) {
  __shared__ __align__(64) __bf16 Ksm[64][64];       // [kv][d] swizzled (key=row&7)
  __shared__ __align__(64) __bf16 Vsm[64][64];       // [d][kv] swizzled
  __shared__ __align__(64) __bf16 Psm[4][16][64];    // per-wave [q][kv] swizzled
  const int tid = threadIdx.x;
  const int wave = tid >> 6, lane = tid & 63;
  const int l15 = lane & 15, quad = lane >> 4;
  const int x7 = l15 & 7, l15h = l15 >> 3;
  const int bh = blockIdx.x;
  const int b = bh >> 5, h = bh & 31, g = h >> 2;

  const int srow = tid >> 2, sc = (tid & 3) * 16;
  const int r7 = srow & 7;
  const int w0 = (((sc >> 3))     ^ r7) * 8;
  const int w1 = (((sc >> 3) + 1) ^ r7) * 8;

  char* kbp = (char*)&Ksm[0][0];
  char* vbp = (char*)&Vsm[0][0];
  char* pbp = (char*)&Psm[0][0][0];
  int kr[2], pr[2], pw[4];
#pragma unroll
  for (int ks = 0; ks < 2; ks++) {
    kr[ks] = l15 * 128 + (((ks * 4 + quad) ^ x7) * 16);
    pr[ks] = wave * 2048 + kr[ks];
  }
#pragma unroll
  for (int nt = 0; nt < 4; nt++)
    pw[nt] = wave * 2048 + quad * 512 + x7 * 2 + (((2 * nt + l15h) ^ ((quad & 1) * 4)) * 16);

  bf16x8 ones;
#pragma unroll
  for (int j = 0; j < 8; j++) ones[j] = (__bf16)1.0f;

  const __bf16* kbase = K + ((size_t)b * S_LEN + srow) * (NKV * HD) + g * HD + sc;
  const __bf16* vbase = Vt + (((size_t)b * NKV + g) * HD + srow) * S_LEN + sc;
  const float QSC = 0.125f * 1.44269504f;   // 1/sqrt(64) * log2(e)

#pragma unroll 1
  for (int half = 0; half < 2; half++) {
    const int qt = half ? (31 - (int)blockIdx.y) : (int)blockIdx.y;
    const int wq0 = qt * 64 + wave * 16;

    const __bf16* qp = Q + ((size_t)(b * S_LEN + wq0 + l15)) * HID + h * HD + quad * 8;
    bf16x8 qf0 = *(const bf16x8*)qp;
    bf16x8 qf1 = *(const bf16x8*)(qp + 32);
    // in-register RoPE + softmax scale (pairs 2j,2j+1 adjacent; fr contiguous)
    const float* fq = fr + (size_t)(wq0 + l15) * HD + quad * 8;
    rope8(qf0, fq, QSC);
    rope8(qf1, fq + 32, QSC);

    f32x4 acc[4] = {};
    f32x4 accs = {};

    const __bf16* kp = kbase;
    const __bf16* vp = vbase;
    uint4 k0 = *(const uint4*)kp, k1 = *(const uint4*)(kp + 8);
    uint4 v0 = *(const uint4*)vp, v1 = *(const uint4*)(vp + 8);

    for (int t = 0; t <= qt; t++) {
      const int kv0 = t * 64;
      __syncthreads();
      *(uint4*)&Ksm[srow][w0] = k0;
      *(uint4*)&Ksm[srow][w1] = k1;
      *(uint4*)&Vsm[srow][w0] = v0;
      *(uint4*)&Vsm[srow][w1] = v1;
      if (t < qt) {
        kp += 64 * NKV * HD;  vp += 64;
        k0 = *(const uint4*)kp; k1 = *(const uint4*)(kp + 8);
        v0 = *(const uint4*)vp; v1 = *(const uint4*)(vp + 8);
      }
      __syncthreads();

      if (kv0 > wq0 + 15) continue;   // fully masked for this wave

      bf16x8 kf[2][4];
#pragma unroll
      for (int ks = 0; ks < 2; ks++)
#pragma unroll
        for (int nt = 0; nt < 4; nt++)
          kf[ks][nt] = *(const bf16x8*)(kbp + (kr[ks] + nt * 2048));

      f32x4 sacc[4] = {};
#pragma unroll
      for (int nt = 0; nt < 4; nt++) {
        sacc[nt] = MFMA16(qf0, kf[0][nt], sacc[nt]);
        sacc[nt] = MFMA16(qf1, kf[1][nt], sacc[nt]);
      }
      const bool domask = (kv0 + 63 > wq0);
#pragma unroll
      for (int nt = 0; nt < 4; nt++) {
        int kv = kv0 + nt * 16 + l15;
        int qr = wq0 + quad * 4;
#pragma unroll
        for (int r = 0; r < 4; r++) {
          float p = __builtin_exp2f(sacc[nt][r]);     // Q pre-scaled by log2e/8
          if (domask && kv > qr + r) p = 0.f;
          *(__bf16*)(pbp + ((pw[nt] ^ (r << 4)) + r * 128)) = (__bf16)p;
        }
      }

      // O += P V ; rsum += P * 1
#pragma unroll
      for (int ks = 0; ks < 2; ks++) {
        bf16x8 vf[4];
#pragma unroll
        for (int nt = 0; nt < 4; nt++)
          vf[nt] = *(const bf16x8*)(vbp + (kr[ks] + nt * 2048));
        bf16x8 pf = *(const bf16x8*)(pbp + pr[ks]);
        accs = MFMA16(pf, ones, accs);
#pragma unroll
        for (int nt = 0; nt < 4; nt++)
          acc[nt] = MFMA16(pf, vf[nt], acc[nt]);
      }
    }

    // epilogue: ones-acc rows (quad*4+r) match O-acc rows -> no shuffles
    __bf16* op = O + ((size_t)(b * S_LEN + wq0 + quad * 4)) * HID + h * HD;
    float inv[4];
#pragma unroll
    for (int r = 0; r < 4; r++) inv[r] = 1.f / accs[r];
#pragma unroll
    for (int nt = 0; nt < 4; nt++)
#pragma unroll
      for (int r = 0; r < 4; r++)
        op[(size_t)r * HID + nt * 16 + l15] = (__bf16)(acc[nt][r] * inv[r]);
  }
}

extern "C" void kernel_launch(void* const* d_in, const int* in_sizes, int n_in,
                              void* d_out, int out_size, void* d_ws, size_t ws_size,
                              hipStream_t stream) {
  (void)in_sizes; (void)n_in; (void)out_size; (void)ws_size;
  const float* x  = (const float*)d_in[0];
  const float* fr = (const float*)d_in[1];
  const float* wq = (const float*)d_in[3];
  const float* bq = (const float*)d_in[4];
  const float* wk = (const float*)d_in[5];
  const float* bk = (const float*)d_in[6];
  const float* wv = (const float*)d_in[7];
  const float* bv = (const float*)d_in[8];
  const float* wo = (const float*)d_in[9];
  const float* bo = (const float*)d_in[10];
  float* out = (float*)d_out;
  char* ws = (char*)d_ws;

  __bf16* xb  = (__bf16*)(ws);
  __bf16* wqb = (__bf16*)(ws + ((size_t)16 << 20));
  __bf16* wkb = (__bf16*)(ws + ((size_t)24 << 20));
  __bf16* wvb = (__bf16*)(ws + ((size_t)26 << 20));
  __bf16* wob = (__bf16*)(ws + ((size_t)28 << 20));
  __bf16* Qb  = (__bf16*)(ws + ((size_t)36 << 20));
  __bf16* Kb  = (__bf16*)(ws + ((size_t)52 << 20));
  __bf16* Vtb = (__bf16*)(ws + ((size_t)60 << 20));
  __bf16* Ab  = (__bf16*)(ws + ((size_t)64 << 20));

  cast_all_k<<<18432, 256, 0, stream>>>(x, wq, wk, wv, wo, xb, wqb, wkb, wvb, wob);

  gemm_qkv_k<<<dim3(32, 24), 256, 0, stream>>>(xb, wqb, wkb, wvb, bq, bk, bv, fr, Qb, Kb, Vtb);

  flash_k<<<dim3(64, 16), 256, 0, stream>>>(Qb, Kb, Vtb, fr, Ab);

  gemm_out_k<<<dim3(32, 16), 256, 0, stream>>>(Ab, wob, bo, out);
}

// Round 6
// 309.558 us; speedup vs baseline: 1.2031x; 1.0183x over previous
//
#include <hip/hip_runtime.h>

#define S_LEN 2048
#define HID   2048
#define NQH   32
#define NKV   8
#define HD    64

#define BM 128
#define BN 128
#define BK 32

typedef __bf16 bf16x8 __attribute__((ext_vector_type(8)));
typedef __bf16 bf16x4 __attribute__((ext_vector_type(4)));
typedef float  f32x4  __attribute__((ext_vector_type(4)));

#define MFMA16(a, b, c) __builtin_amdgcn_mfma_f32_16x16x32_bf16(a, b, c, 0, 0, 0)

__device__ __forceinline__ void async_copy16(const void* g, void* l) {
  __builtin_amdgcn_global_load_lds(
      (const __attribute__((address_space(1))) unsigned int*)g,
      (__attribute__((address_space(3))) unsigned int*)l, 16, 0, 0);
}

__device__ __forceinline__ unsigned cvtpk_bf16(float lo, float hi) {
  unsigned r;
  asm("v_cvt_pk_bf16_f32 %0, %1, %2" : "=v"(r) : "v"(lo), "v"(hi));
  return r;
}

// ---------------- fused f32 -> bf16 cast of x + all weights ----------------
__global__ void cast_all_k(const float* __restrict__ x,  const float* __restrict__ wq,
                           const float* __restrict__ wk, const float* __restrict__ wv,
                           const float* __restrict__ wo,
                           __bf16* __restrict__ xb,  __bf16* __restrict__ wqb,
                           __bf16* __restrict__ wkb, __bf16* __restrict__ wvb,
                           __bf16* __restrict__ wob) {
  int bid = blockIdx.x;
  const float* in; __bf16* out; int base;
  if (bid < 8192)       { in = x;  out = xb;  base = bid; }
  else if (bid < 12288) { in = wq; out = wqb; base = bid - 8192; }
  else if (bid < 13312) { in = wk; out = wkb; base = bid - 12288; }
  else if (bid < 14336) { in = wv; out = wvb; base = bid - 13312; }
  else                  { in = wo; out = wob; base = bid - 14336; }
  int i = (base * 256 + threadIdx.x) * 4;
  float4 v = *(const float4*)(in + i);
  bf16x4 o;
  o[0] = (__bf16)v.x; o[1] = (__bf16)v.y; o[2] = (__bf16)v.z; o[3] = (__bf16)v.w;
  *(bf16x4*)(out + i) = o;
}

// ---------------- 128x128 BK=32 co-resident GEMM core (m97-class) ----------------
__device__ __forceinline__ void gemm_pipe(const __bf16* __restrict__ A,
                                          const __bf16* __restrict__ B,
                                          int m0, int n0, int K,
                                          __bf16 (&As)[2][BM][BK],
                                          __bf16 (&Bs)[2][BN][BK],
                                          f32x4 (&acc)[4][4]) {
  const int tid = threadIdx.x, wave = tid >> 6, lane = tid & 63;
  const int l15 = lane & 15, quad = lane >> 4;
  const int wr = wave >> 1, wc = wave & 1;

  const int srow   = tid >> 2;
  const int schunk = (tid & 3) ^ ((tid >> 3) & 3);
  const __bf16* ga = A + (size_t)(m0 + srow) * K + schunk * 8;
  const __bf16* gb = B + (size_t)(n0 + srow) * K + schunk * 8;

  const int co = (quad ^ ((l15 >> 1) & 3)) * 8;

  const int NT = K / BK;

#define STAGE(st, kt) do {                                              \
    async_copy16(ga + (kt),                  &As[st][wave * 16][0]);    \
    async_copy16(ga + (kt) + (size_t)64 * K, &As[st][64 + wave * 16][0]); \
    async_copy16(gb + (kt),                  &Bs[st][wave * 16][0]);    \
    async_copy16(gb + (kt) + (size_t)64 * K, &Bs[st][64 + wave * 16][0]); \
  } while (0)

  STAGE(0, 0);
  asm volatile("s_waitcnt vmcnt(0)" ::: "memory");
  __builtin_amdgcn_s_barrier();
  asm volatile("" ::: "memory");

  int s = 0;
#pragma unroll 2
  for (int t = 0; t < NT; t++) {
    if (t + 1 < NT) STAGE(s ^ 1, (t + 1) * BK);

    const __bf16* a0 = &As[s][wr * 64][0];
    const __bf16* b0 = &Bs[s][wc * 64][0];
    bf16x8 af[4], bfr[4];
#pragma unroll
    for (int mt = 0; mt < 4; mt++)
      af[mt] = *(const bf16x8*)(a0 + (mt * 16 + l15) * BK + co);
#pragma unroll
    for (int nt = 0; nt < 4; nt++)
      bfr[nt] = *(const bf16x8*)(b0 + (nt * 16 + l15) * BK + co);

    __builtin_amdgcn_s_setprio(1);
#pragma unroll
    for (int mt = 0; mt < 4; mt++)
#pragma unroll
      for (int nt = 0; nt < 4; nt++)
        acc[mt][nt] = MFMA16(af[mt], bfr[nt], acc[mt][nt]);
    __builtin_amdgcn_s_setprio(0);

    asm volatile("s_waitcnt vmcnt(0) lgkmcnt(0)" ::: "memory");
    __builtin_amdgcn_s_barrier();
    asm volatile("" ::: "memory");
    s ^= 1;
  }
#undef STAGE
}

// fused QKV projection + RoPE(K) + V transpose. grid (32, 24), 256 thr.
__global__ __launch_bounds__(256, 4) void gemm_qkv_k(const __bf16* __restrict__ xb,
    const __bf16* __restrict__ wqb, const __bf16* __restrict__ wkb, const __bf16* __restrict__ wvb,
    const float* __restrict__ bq, const float* __restrict__ bk, const float* __restrict__ bv,
    const float* __restrict__ fr,
    __bf16* __restrict__ Qb, __bf16* __restrict__ Kb, __bf16* __restrict__ Vt) {
  __shared__ __align__(16) __bf16 As[2][BM][BK];
  __shared__ __align__(16) __bf16 Bs[2][BN][BK];
  const int by = blockIdx.y;
  const int m0 = blockIdx.x * BM;
  const __bf16* B; const float* bias; int n0;
  int mode;  // 0 = plain Q, 1 = ropeK, 2 = vtrans
  if (by < 16)      { B = wqb; bias = bq; n0 = by * 128;        mode = 0; }
  else if (by < 20) { B = wkb; bias = bk; n0 = (by - 16) * 128; mode = 1; }
  else              { B = wvb; bias = bv; n0 = (by - 20) * 128; mode = 2; }

  f32x4 acc[4][4] = {};
  gemm_pipe(xb, B, m0, n0, HID, As, Bs, acc);

  const int tid = threadIdx.x, wave = tid >> 6, lane = tid & 63;
  const int l15 = lane & 15, quad = lane >> 4;
  const int wr = wave >> 1, wc = wave & 1;

  if (mode == 2) {
#pragma unroll
    for (int nt = 0; nt < 4; nt++) {
      int col = n0 + wc * 64 + nt * 16 + l15;       // 0..511
      int g = col >> 6, d = col & 63;
      float bv2 = bias[col];
#pragma unroll
      for (int mt = 0; mt < 4; mt++) {
        int row = m0 + wr * 64 + mt * 16 + quad * 4;
        int b = row >> 11, sI = row & 2047;
        bf16x4 o;
#pragma unroll
        for (int r = 0; r < 4; r++) o[r] = (__bf16)(acc[mt][nt][r] + bv2);
        *(bf16x4*)(Vt + (((size_t)(b * NKV + g) * HD + d)) * S_LEN + sI) = o;
      }
    }
  } else if (mode == 0) {
#pragma unroll
    for (int nt = 0; nt < 4; nt++) {
      int col = n0 + wc * 64 + nt * 16 + l15;
      float bv2 = bias[col];
#pragma unroll
      for (int mt = 0; mt < 4; mt++) {
        int row = m0 + wr * 64 + mt * 16 + quad * 4;
#pragma unroll
        for (int r = 0; r < 4; r++)
          Qb[(size_t)(row + r) * HID + col] = (__bf16)(acc[mt][nt][r] + bv2);
      }
    }
  } else {
    const int dpar = l15 & 1;
#pragma unroll
    for (int nt = 0; nt < 4; nt++) {
      int col = n0 + wc * 64 + nt * 16 + l15;
      int d = col & 63;
      float bv2 = bias[col];
#pragma unroll
      for (int mt = 0; mt < 4; mt++) {
        int row = m0 + wr * 64 + mt * 16 + quad * 4;
        int sI = row & 2047;
#pragma unroll
        for (int r = 0; r < 4; r++) {
          float v = acc[mt][nt][r] + bv2;
          float p = __shfl_xor(v, 1, 64);
          float f = fr[(size_t)(sI + r) * HD + d];
          float fp = __shfl_xor(f, 1, 64);
          float o = dpar ? (p * f + v * fp) : (v * f - p * fp);
          Kb[(size_t)(row + r) * 512 + col] = (__bf16)o;
        }
      }
    }
  }
}

// output projection: grid (32, 16) = 512 blocks
__global__ __launch_bounds__(256, 4) void gemm_out_k(const __bf16* __restrict__ A,
    const __bf16* __restrict__ Bw, const float* __restrict__ bias, float* __restrict__ C) {
  __shared__ __align__(16) __bf16 As[2][BM][BK];
  __shared__ __align__(16) __bf16 Bs[2][BN][BK];
  const int m0 = blockIdx.x * BM, n0 = blockIdx.y * BN;
  f32x4 acc[4][4] = {};
  gemm_pipe(A, Bw, m0, n0, HID, As, Bs, acc);
  const int tid = threadIdx.x, wave = tid >> 6, lane = tid & 63;
  const int l15 = lane & 15, quad = lane >> 4;
  const int wr = wave >> 1, wc = wave & 1;
#pragma unroll
  for (int nt = 0; nt < 4; nt++) {
    int col = n0 + wc * 64 + nt * 16 + l15;
    float bv = bias[col];
#pragma unroll
    for (int mt = 0; mt < 4; mt++) {
      int row = m0 + wr * 64 + mt * 16 + quad * 4;
#pragma unroll
      for (int r = 0; r < 4; r++)
        C[(size_t)(row + r) * HID + col] = acc[mt][nt][r] + bv;
    }
  }
}

// RoPE a bf16x8 (pairs 2j,2j+1 adjacent) with contiguous f32 freqs, fused scale.
__device__ __forceinline__ void rope8(bf16x8& q, const float* f, float sc) {
  float4 fa = *(const float4*)f;
  float4 fb = *(const float4*)(f + 4);
  float e, o;
  e = (float)q[0]; o = (float)q[1];
  q[0] = (__bf16)((e * fa.x - o * fa.y) * sc);
  q[1] = (__bf16)((e * fa.y + o * fa.x) * sc);
  e = (float)q[2]; o = (float)q[3];
  q[2] = (__bf16)((e * fa.z - o * fa.w) * sc);
  q[3] = (__bf16)((e * fa.w + o * fa.z) * sc);
  e = (float)q[4]; o = (float)q[5];
  q[4] = (__bf16)((e * fb.x - o * fb.y) * sc);
  q[5] = (__bf16)((e * fb.y + o * fb.x) * sc);
  e = (float)q[6]; o = (float)q[7];
  q[6] = (__bf16)((e * fb.z - o * fb.w) * sc);
  q[7] = (__bf16)((e * fb.w + o * fb.z) * sc);
}

// ---------------- Flash attention v8: swapped QK^T + in-register softmax ----------------
// Block y does q-tile pair (y, 31-y): 33 kv-iters every block. 4 waves x 16 q-rows.
// QK^T computed as mfma(K, Q) -> lane holds S^T col q = l15 (full row lane-local).
// K A-fragment rows permuted by sigma so PV fragment assembly is EXACTLY
// 2x v_permlane32_swap_b32 per ks (T12). P packed via v_cvt_pk_bf16_f32.
// No P LDS buffer. K/V double-buffered -> ONE __syncthreads per kv-iter.
__global__ __launch_bounds__(256, 4) void flash_k(const __bf16* __restrict__ Q,
                                                  const __bf16* __restrict__ K,
                                                  const __bf16* __restrict__ Vt,
                                                  const float* __restrict__ fr,
                                                  __bf16* __restrict__ O) {
  __shared__ __align__(64) __bf16 Ksm[2][64][64];    // [buf][kv][d] swizzled (key=row&7)
  __shared__ __align__(64) __bf16 Vsm[2][64][64];    // [buf][d][kv] swizzled
  const int tid = threadIdx.x;
  const int wave = tid >> 6, lane = tid & 63;
  const int l15 = lane & 15, quad = lane >> 4;
  const int bh = blockIdx.x;
  const int b = bh >> 5, h = bh & 31, g = h >> 2;

  const int srow = tid >> 2, sc = (tid & 3) * 16;
  const int r7 = srow & 7;
  const int w0 = (((sc >> 3))     ^ r7) * 8;
  const int w1 = (((sc >> 3) + 1) ^ r7) * 8;

  const char* kbp = (const char*)&Ksm[0][0][0];
  const char* vbp = (const char*)&Vsm[0][0][0];

  // sigma row permutation: logical row rho -> physical kv16 = 8*(rho2)+4*(rho3)+(rho&3)
  const int x7  = l15 & 7;
  const int sig = 8 * ((l15 >> 2) & 1) + 4 * (l15 >> 3) + (l15 & 3);
  const int s7  = sig & 7;
  int krK[2], krV[2];
#pragma unroll
  for (int ks = 0; ks < 2; ks++) {
    krK[ks] = sig * 128 + (((ks * 4 + quad) ^ s7) * 16);
    krV[ks] = l15 * 128 + (((ks * 4 + quad) ^ x7) * 16);
  }
  // lane's S rows: physical kv within 16-tile = kvb + r
  const int kvb = 8 * (quad & 1) + 4 * (quad >> 1);

  bf16x8 ones;
#pragma unroll
  for (int j = 0; j < 8; j++) ones[j] = (__bf16)1.0f;

  const __bf16* kbase = K + ((size_t)b * S_LEN + srow) * (NKV * HD) + g * HD + sc;
  const __bf16* vbase = Vt + (((size_t)b * NKV + g) * HD + srow) * S_LEN + sc;
  const float QSC = 0.125f * 1.44269504f;   // 1/sqrt(64) * log2(e)
  const int KSTEP = 64 * NKV * HD;

#pragma unroll 1
  for (int half = 0; half < 2; half++) {
    const int qt = half ? (31 - (int)blockIdx.y) : (int)blockIdx.y;
    const int wq0 = qt * 64 + wave * 16;

    const __bf16* qp = Q + ((size_t)(b * S_LEN + wq0 + l15)) * HID + h * HD + quad * 8;
    bf16x8 qf0 = *(const bf16x8*)qp;
    bf16x8 qf1 = *(const bf16x8*)(qp + 32);
    const float* fq = fr + (size_t)(wq0 + l15) * HD + quad * 8;
    rope8(qf0, fq, QSC);
    rope8(qf1, fq + 32, QSC);

    f32x4 acc[4] = {};
    f32x4 accs = {};

    const __bf16* kp = kbase;
    const __bf16* vp = vbase;
    uint4 k0 = *(const uint4*)kp, k1 = *(const uint4*)(kp + 8);
    uint4 v0 = *(const uint4*)vp, v1 = *(const uint4*)(vp + 8);
    // stage tile 0 into buf 0
    *(uint4*)&Ksm[0][srow][w0] = k0;
    *(uint4*)&Ksm[0][srow][w1] = k1;
    *(uint4*)&Vsm[0][srow][w0] = v0;
    *(uint4*)&Vsm[0][srow][w1] = v1;
    if (qt > 0) {   // prefetch tile 1
      kp += KSTEP;  vp += 64;
      k0 = *(const uint4*)kp; k1 = *(const uint4*)(kp + 8);
      v0 = *(const uint4*)vp; v1 = *(const uint4*)(vp + 8);
    }
    __syncthreads();

#pragma unroll 1
    for (int t = 0; t <= qt; t++) {
      const int cur = t & 1;
      const int kv0 = t * 64;

      if (t < qt) {   // write tile t+1 into the other buffer (freed last barrier)
        *(uint4*)&Ksm[cur ^ 1][srow][w0] = k0;
        *(uint4*)&Ksm[cur ^ 1][srow][w1] = k1;
        *(uint4*)&Vsm[cur ^ 1][srow][w0] = v0;
        *(uint4*)&Vsm[cur ^ 1][srow][w1] = v1;
        if (t + 2 <= qt) {   // prefetch tile t+2
          kp += KSTEP;  vp += 64;
          k0 = *(const uint4*)kp; k1 = *(const uint4*)(kp + 8);
          v0 = *(const uint4*)vp; v1 = *(const uint4*)(vp + 8);
        }
      }

      if (kv0 <= wq0 + 15) {   // not fully masked for this wave
        const int cb = cur * 8192;
        bf16x8 kf[2][4];
#pragma unroll
        for (int ks = 0; ks < 2; ks++)
#pragma unroll
          for (int nt = 0; nt < 4; nt++)
            kf[ks][nt] = *(const bf16x8*)(kbp + cb + krK[ks] + nt * 2048);

        // swapped QK^T: D[kv][q], lane holds q = l15, kv = kv0+16nt+kvb+r
        f32x4 sacc[4] = {};
#pragma unroll
        for (int nt = 0; nt < 4; nt++) {
          sacc[nt] = MFMA16(kf[0][nt], qf0, sacc[nt]);
          sacc[nt] = MFMA16(kf[1][nt], qf1, sacc[nt]);
        }

        const bool domask = (kv0 + 63 > wq0);
        const int md = wq0 + l15 - kv0 - kvb;   // mask if 16*nt + r > md
        unsigned W[4][2];
#pragma unroll
        for (int nt = 0; nt < 4; nt++) {
          f32x4 pv;
#pragma unroll
          for (int r = 0; r < 4; r++) pv[r] = __builtin_exp2f(sacc[nt][r]);
          if (domask) {
#pragma unroll
            for (int r = 0; r < 4; r++)
              if (nt * 16 + r > md) pv[r] = 0.f;
          }
          W[nt][0] = cvtpk_bf16(pv[0], pv[1]);
          W[nt][1] = cvtpk_bf16(pv[2], pv[3]);
        }

        // PV: per ks, 2 permlane32_swap assemble the full A-fragment
#pragma unroll
        for (int ks = 0; ks < 2; ks++) {
          unsigned a0 = W[2 * ks][0], b0 = W[2 * ks + 1][0];
          unsigned a1 = W[2 * ks][1], b1 = W[2 * ks + 1][1];
          asm("v_permlane32_swap_b32 %0, %1" : "+v"(a0), "+v"(b0));
          asm("v_permlane32_swap_b32 %0, %1" : "+v"(a1), "+v"(b1));
          union { unsigned u[4]; bf16x8 v; } pk;
          pk.u[0] = a0; pk.u[1] = a1; pk.u[2] = b0; pk.u[3] = b1;
          bf16x8 pf = pk.v;

          bf16x8 vf[4];
#pragma unroll
          for (int nt = 0; nt < 4; nt++)
            vf[nt] = *(const bf16x8*)(vbp + cb + krV[ks] + nt * 2048);
          accs = MFMA16(pf, ones, accs);
#pragma unroll
          for (int nt = 0; nt < 4; nt++)
            acc[nt] = MFMA16(pf, vf[nt], acc[nt]);
        }
      }

      __syncthreads();
    }

    // epilogue: ones-acc rows (quad*4+r) match O-acc rows -> no shuffles
    __bf16* op = O + ((size_t)(b * S_LEN + wq0 + quad * 4)) * HID + h * HD;
    float inv[4];
#pragma unroll
    for (int r = 0; r < 4; r++) inv[r] = 1.f / accs[r];
#pragma unroll
    for (int nt = 0; nt < 4; nt++)
#pragma unroll
      for (int r = 0; r < 4; r++)
        op[(size_t)r * HID + nt * 16 + l15] = (__bf16)(acc[nt][r] * inv[r]);
  }
}

extern "C" void kernel_launch(void* const* d_in, const int* in_sizes, int n_in,
                              void* d_out, int out_size, void* d_ws, size_t ws_size,
                              hipStream_t stream) {
  (void)in_sizes; (void)n_in; (void)out_size; (void)ws_size;
  const float* x  = (const float*)d_in[0];
  const float* fr = (const float*)d_in[1];
  const float* wq = (const float*)d_in[3];
  const float* bq = (const float*)d_in[4];
  const float* wk = (const float*)d_in[5];
  const float* bk = (const float*)d_in[6];
  const float* wv = (const float*)d_in[7];
  const float* bv = (const float*)d_in[8];
  const float* wo = (const float*)d_in[9];
  const float* bo = (const float*)d_in[10];
  float* out = (float*)d_out;
  char* ws = (char*)d_ws;

  __bf16* xb  = (__bf16*)(ws);
  __bf16* wqb = (__bf16*)(ws + ((size_t)16 << 20));
  __bf16* wkb = (__bf16*)(ws + ((size_t)24 << 20));
  __bf16* wvb = (__bf16*)(ws + ((size_t)26 << 20));
  __bf16* wob = (__bf16*)(ws + ((size_t)28 << 20));
  __bf16* Qb  = (__bf16*)(ws + ((size_t)36 << 20));
  __bf16* Kb  = (__bf16*)(ws + ((size_t)52 << 20));
  __bf16* Vtb = (__bf16*)(ws + ((size_t)60 << 20));
  __bf16* Ab  = (__bf16*)(ws + ((size_t)64 << 20));

  cast_all_k<<<18432, 256, 0, stream>>>(x, wq, wk, wv, wo, xb, wqb, wkb, wvb, wob);

  gemm_qkv_k<<<dim3(32, 24), 256, 0, stream>>>(xb, wqb, wkb, wvb, bq, bk, bv, fr, Qb, Kb, Vtb);

  flash_k<<<dim3(64, 16), 256, 0, stream>>>(Qb, Kb, Vtb, fr, Ab);

  gemm_out_k<<<dim3(32, 16), 256, 0, stream>>>(Ab, wob, bo, out);
}

// Round 7
// 309.057 us; speedup vs baseline: 1.2051x; 1.0016x over previous
//
#include <hip/hip_runtime.h>

#define S_LEN 2048
#define HID   2048
#define NQH   32
#define NKV   8
#define HD    64

#define BM 128
#define BN 128
#define BK 32

typedef __bf16 bf16x8 __attribute__((ext_vector_type(8)));
typedef __bf16 bf16x4 __attribute__((ext_vector_type(4)));
typedef float  f32x4  __attribute__((ext_vector_type(4)));

#define MFMA16(a, b, c) __builtin_amdgcn_mfma_f32_16x16x32_bf16(a, b, c, 0, 0, 0)

__device__ __forceinline__ void async_copy16(const void* g, void* l) {
  __builtin_amdgcn_global_load_lds(
      (const __attribute__((address_space(1))) unsigned int*)g,
      (__attribute__((address_space(3))) unsigned int*)l, 16, 0, 0);
}

__device__ __forceinline__ unsigned cvtpk_bf16(float lo, float hi) {
  unsigned r;
  asm("v_cvt_pk_bf16_f32 %0, %1, %2" : "=v"(r) : "v"(lo), "v"(hi));
  return r;
}

// ---------------- fused f32 -> bf16 cast of x + all weights ----------------
__global__ void cast_all_k(const float* __restrict__ x,  const float* __restrict__ wq,
                           const float* __restrict__ wk, const float* __restrict__ wv,
                           const float* __restrict__ wo,
                           __bf16* __restrict__ xb,  __bf16* __restrict__ wqb,
                           __bf16* __restrict__ wkb, __bf16* __restrict__ wvb,
                           __bf16* __restrict__ wob) {
  int bid = blockIdx.x;
  const float* in; __bf16* out; int base;
  if (bid < 8192)       { in = x;  out = xb;  base = bid; }
  else if (bid < 12288) { in = wq; out = wqb; base = bid - 8192; }
  else if (bid < 13312) { in = wk; out = wkb; base = bid - 12288; }
  else if (bid < 14336) { in = wv; out = wvb; base = bid - 13312; }
  else                  { in = wo; out = wob; base = bid - 14336; }
  int i = (base * 256 + threadIdx.x) * 4;
  float4 v = *(const float4*)(in + i);
  bf16x4 o;
  o[0] = (__bf16)v.x; o[1] = (__bf16)v.y; o[2] = (__bf16)v.z; o[3] = (__bf16)v.w;
  *(bf16x4*)(out + i) = o;
}

// ---------------- 128x128 BK=32 GEMM core, 3-stage counted-vmcnt pipeline ----------------
// 256 thr / 4 waves (2x2), per-wave 64x64. LDS 3 x (8+8) KiB = 48 KiB -> 3 blocks/CU.
// Per K-tile: vmcnt(4) [tile t's stage, issued at t-2 -> free; t+1's 4 loads stay
// in flight across the barrier] -> ONE barrier -> STAGE(t+2) -> 8 ds_read + 16 MFMA.
// No lgkm drain: buffer restaged at tile t was last read at t-1, and those reads
// completed before their consuming MFMAs (compiler lgkm waits) -> before each
// wave's barrier arrival. Distance-2 WAR certified by the barrier alone.
// T2 swizzle: chunk key k(row)=(row>>1)&3; gload_lds dest linear, SOURCE pre-XOR'd.
__device__ __forceinline__ void gemm_pipe(const __bf16* __restrict__ A,
                                          const __bf16* __restrict__ B,
                                          int m0, int n0, int K,
                                          __bf16 (&As)[3][BM][BK],
                                          __bf16 (&Bs)[3][BN][BK],
                                          f32x4 (&acc)[4][4]) {
  const int tid = threadIdx.x, wave = tid >> 6, lane = tid & 63;
  const int l15 = lane & 15, quad = lane >> 4;
  const int wr = wave >> 1, wc = wave & 1;

  const int srow   = tid >> 2;
  const int schunk = (tid & 3) ^ ((tid >> 3) & 3);
  const __bf16* ga = A + (size_t)(m0 + srow) * K + schunk * 8;
  const __bf16* gb = B + (size_t)(n0 + srow) * K + schunk * 8;

  const int co = (quad ^ ((l15 >> 1) & 3)) * 8;

  const int NT = K / BK;

#define STAGE(st, kt) do {                                              \
    async_copy16(ga + (kt),                  &As[st][wave * 16][0]);    \
    async_copy16(ga + (kt) + (size_t)64 * K, &As[st][64 + wave * 16][0]); \
    async_copy16(gb + (kt),                  &Bs[st][wave * 16][0]);    \
    async_copy16(gb + (kt) + (size_t)64 * K, &Bs[st][64 + wave * 16][0]); \
  } while (0)

  STAGE(0, 0);
  STAGE(1, BK);

  int s = 0;
#pragma unroll 1
  for (int t = 0; t < NT; t++) {
    if (t + 1 < NT) asm volatile("s_waitcnt vmcnt(4)" ::: "memory");
    else            asm volatile("s_waitcnt vmcnt(0)" ::: "memory");
    __builtin_amdgcn_s_barrier();
    asm volatile("" ::: "memory");

    if (t + 2 < NT) {
      int s2 = s + 2; if (s2 >= 3) s2 -= 3;
      STAGE(s2, (t + 2) * BK);
    }

    const __bf16* a0 = &As[s][wr * 64][0];
    const __bf16* b0 = &Bs[s][wc * 64][0];
    bf16x8 af[4], bfr[4];
#pragma unroll
    for (int mt = 0; mt < 4; mt++)
      af[mt] = *(const bf16x8*)(a0 + (mt * 16 + l15) * BK + co);
#pragma unroll
    for (int nt = 0; nt < 4; nt++)
      bfr[nt] = *(const bf16x8*)(b0 + (nt * 16 + l15) * BK + co);

    __builtin_amdgcn_s_setprio(1);
#pragma unroll
    for (int mt = 0; mt < 4; mt++)
#pragma unroll
      for (int nt = 0; nt < 4; nt++)
        acc[mt][nt] = MFMA16(af[mt], bfr[nt], acc[mt][nt]);
    __builtin_amdgcn_s_setprio(0);

    s = s + 1; if (s >= 3) s -= 3;
  }
#undef STAGE
}

// fused QKV projection + RoPE(K) + V transpose. grid (32, 24), 256 thr.
__global__ __launch_bounds__(256, 3) void gemm_qkv_k(const __bf16* __restrict__ xb,
    const __bf16* __restrict__ wqb, const __bf16* __restrict__ wkb, const __bf16* __restrict__ wvb,
    const float* __restrict__ bq, const float* __restrict__ bk, const float* __restrict__ bv,
    const float* __restrict__ fr,
    __bf16* __restrict__ Qb, __bf16* __restrict__ Kb, __bf16* __restrict__ Vt) {
  __shared__ __align__(16) __bf16 As[3][BM][BK];
  __shared__ __align__(16) __bf16 Bs[3][BN][BK];
  const int by = blockIdx.y;
  const int m0 = blockIdx.x * BM;
  const __bf16* B; const float* bias; int n0;
  int mode;  // 0 = plain Q, 1 = ropeK, 2 = vtrans
  if (by < 16)      { B = wqb; bias = bq; n0 = by * 128;        mode = 0; }
  else if (by < 20) { B = wkb; bias = bk; n0 = (by - 16) * 128; mode = 1; }
  else              { B = wvb; bias = bv; n0 = (by - 20) * 128; mode = 2; }

  f32x4 acc[4][4] = {};
  gemm_pipe(xb, B, m0, n0, HID, As, Bs, acc);

  const int tid = threadIdx.x, wave = tid >> 6, lane = tid & 63;
  const int l15 = lane & 15, quad = lane >> 4;
  const int wr = wave >> 1, wc = wave & 1;

  if (mode == 2) {
#pragma unroll
    for (int nt = 0; nt < 4; nt++) {
      int col = n0 + wc * 64 + nt * 16 + l15;       // 0..511
      int g = col >> 6, d = col & 63;
      float bv2 = bias[col];
#pragma unroll
      for (int mt = 0; mt < 4; mt++) {
        int row = m0 + wr * 64 + mt * 16 + quad * 4;
        int b = row >> 11, sI = row & 2047;
        bf16x4 o;
#pragma unroll
        for (int r = 0; r < 4; r++) o[r] = (__bf16)(acc[mt][nt][r] + bv2);
        *(bf16x4*)(Vt + (((size_t)(b * NKV + g) * HD + d)) * S_LEN + sI) = o;
      }
    }
  } else if (mode == 0) {
#pragma unroll
    for (int nt = 0; nt < 4; nt++) {
      int col = n0 + wc * 64 + nt * 16 + l15;
      float bv2 = bias[col];
#pragma unroll
      for (int mt = 0; mt < 4; mt++) {
        int row = m0 + wr * 64 + mt * 16 + quad * 4;
#pragma unroll
        for (int r = 0; r < 4; r++)
          Qb[(size_t)(row + r) * HID + col] = (__bf16)(acc[mt][nt][r] + bv2);
      }
    }
  } else {
    const int dpar = l15 & 1;
#pragma unroll
    for (int nt = 0; nt < 4; nt++) {
      int col = n0 + wc * 64 + nt * 16 + l15;
      int d = col & 63;
      float bv2 = bias[col];
#pragma unroll
      for (int mt = 0; mt < 4; mt++) {
        int row = m0 + wr * 64 + mt * 16 + quad * 4;
        int sI = row & 2047;
#pragma unroll
        for (int r = 0; r < 4; r++) {
          float v = acc[mt][nt][r] + bv2;
          float p = __shfl_xor(v, 1, 64);
          float f = fr[(size_t)(sI + r) * HD + d];
          float fp = __shfl_xor(f, 1, 64);
          float o = dpar ? (p * f + v * fp) : (v * f - p * fp);
          Kb[(size_t)(row + r) * 512 + col] = (__bf16)o;
        }
      }
    }
  }
}

// output projection: grid (32, 16) = 512 blocks
__global__ __launch_bounds__(256, 3) void gemm_out_k(const __bf16* __restrict__ A,
    const __bf16* __restrict__ Bw, const float* __restrict__ bias, float* __restrict__ C) {
  __shared__ __align__(16) __bf16 As[3][BM][BK];
  __shared__ __align__(16) __bf16 Bs[3][BN][BK];
  const int m0 = blockIdx.x * BM, n0 = blockIdx.y * BN;
  f32x4 acc[4][4] = {};
  gemm_pipe(A, Bw, m0, n0, HID, As, Bs, acc);
  const int tid = threadIdx.x, wave = tid >> 6, lane = tid & 63;
  const int l15 = lane & 15, quad = lane >> 4;
  const int wr = wave >> 1, wc = wave & 1;
#pragma unroll
  for (int nt = 0; nt < 4; nt++) {
    int col = n0 + wc * 64 + nt * 16 + l15;
    float bv = bias[col];
#pragma unroll
    for (int mt = 0; mt < 4; mt++) {
      int row = m0 + wr * 64 + mt * 16 + quad * 4;
#pragma unroll
      for (int r = 0; r < 4; r++)
        C[(size_t)(row + r) * HID + col] = acc[mt][nt][r] + bv;
    }
  }
}

// RoPE a bf16x8 (pairs 2j,2j+1 adjacent) with contiguous f32 freqs, fused scale.
__device__ __forceinline__ void rope8(bf16x8& q, const float* f, float sc) {
  float4 fa = *(const float4*)f;
  float4 fb = *(const float4*)(f + 4);
  float e, o;
  e = (float)q[0]; o = (float)q[1];
  q[0] = (__bf16)((e * fa.x - o * fa.y) * sc);
  q[1] = (__bf16)((e * fa.y + o * fa.x) * sc);
  e = (float)q[2]; o = (float)q[3];
  q[2] = (__bf16)((e * fa.z - o * fa.w) * sc);
  q[3] = (__bf16)((e * fa.w + o * fa.z) * sc);
  e = (float)q[4]; o = (float)q[5];
  q[4] = (__bf16)((e * fb.x - o * fb.y) * sc);
  q[5] = (__bf16)((e * fb.y + o * fb.x) * sc);
  e = (float)q[6]; o = (float)q[7];
  q[6] = (__bf16)((e * fb.z - o * fb.w) * sc);
  q[7] = (__bf16)((e * fb.w + o * fb.z) * sc);
}

// ---------------- Flash attention v8: swapped QK^T + in-register softmax ----------------
__global__ __launch_bounds__(256, 4) void flash_k(const __bf16* __restrict__ Q,
                                                  const __bf16* __restrict__ K,
                                                  const __bf16* __restrict__ Vt,
                                                  const float* __restrict__ fr,
                                                  __bf16* __restrict__ O) {
  __shared__ __align__(64) __bf16 Ksm[2][64][64];    // [buf][kv][d] swizzled (key=row&7)
  __shared__ __align__(64) __bf16 Vsm[2][64][64];    // [buf][d][kv] swizzled
  const int tid = threadIdx.x;
  const int wave = tid >> 6, lane = tid & 63;
  const int l15 = lane & 15, quad = lane >> 4;
  const int bh = blockIdx.x;
  const int b = bh >> 5, h = bh & 31, g = h >> 2;

  const int srow = tid >> 2, sc = (tid & 3) * 16;
  const int r7 = srow & 7;
  const int w0 = (((sc >> 3))     ^ r7) * 8;
  const int w1 = (((sc >> 3) + 1) ^ r7) * 8;

  const char* kbp = (const char*)&Ksm[0][0][0];
  const char* vbp = (const char*)&Vsm[0][0][0];

  const int x7  = l15 & 7;
  const int sig = 8 * ((l15 >> 2) & 1) + 4 * (l15 >> 3) + (l15 & 3);
  const int s7  = sig & 7;
  int krK[2], krV[2];
#pragma unroll
  for (int ks = 0; ks < 2; ks++) {
    krK[ks] = sig * 128 + (((ks * 4 + quad) ^ s7) * 16);
    krV[ks] = l15 * 128 + (((ks * 4 + quad) ^ x7) * 16);
  }
  const int kvb = 8 * (quad & 1) + 4 * (quad >> 1);

  bf16x8 ones;
#pragma unroll
  for (int j = 0; j < 8; j++) ones[j] = (__bf16)1.0f;

  const __bf16* kbase = K + ((size_t)b * S_LEN + srow) * (NKV * HD) + g * HD + sc;
  const __bf16* vbase = Vt + (((size_t)b * NKV + g) * HD + srow) * S_LEN + sc;
  const float QSC = 0.125f * 1.44269504f;   // 1/sqrt(64) * log2(e)
  const int KSTEP = 64 * NKV * HD;

#pragma unroll 1
  for (int half = 0; half < 2; half++) {
    const int qt = half ? (31 - (int)blockIdx.y) : (int)blockIdx.y;
    const int wq0 = qt * 64 + wave * 16;

    const __bf16* qp = Q + ((size_t)(b * S_LEN + wq0 + l15)) * HID + h * HD + quad * 8;
    bf16x8 qf0 = *(const bf16x8*)qp;
    bf16x8 qf1 = *(const bf16x8*)(qp + 32);
    const float* fq = fr + (size_t)(wq0 + l15) * HD + quad * 8;
    rope8(qf0, fq, QSC);
    rope8(qf1, fq + 32, QSC);

    f32x4 acc[4] = {};
    f32x4 accs = {};

    const __bf16* kp = kbase;
    const __bf16* vp = vbase;
    uint4 k0 = *(const uint4*)kp, k1 = *(const uint4*)(kp + 8);
    uint4 v0 = *(const uint4*)vp, v1 = *(const uint4*)(vp + 8);
    *(uint4*)&Ksm[0][srow][w0] = k0;
    *(uint4*)&Ksm[0][srow][w1] = k1;
    *(uint4*)&Vsm[0][srow][w0] = v0;
    *(uint4*)&Vsm[0][srow][w1] = v1;
    if (qt > 0) {
      kp += KSTEP;  vp += 64;
      k0 = *(const uint4*)kp; k1 = *(const uint4*)(kp + 8);
      v0 = *(const uint4*)vp; v1 = *(const uint4*)(vp + 8);
    }
    __syncthreads();

#pragma unroll 1
    for (int t = 0; t <= qt; t++) {
      const int cur = t & 1;
      const int kv0 = t * 64;

      if (t < qt) {
        *(uint4*)&Ksm[cur ^ 1][srow][w0] = k0;
        *(uint4*)&Ksm[cur ^ 1][srow][w1] = k1;
        *(uint4*)&Vsm[cur ^ 1][srow][w0] = v0;
        *(uint4*)&Vsm[cur ^ 1][srow][w1] = v1;
        if (t + 2 <= qt) {
          kp += KSTEP;  vp += 64;
          k0 = *(const uint4*)kp; k1 = *(const uint4*)(kp + 8);
          v0 = *(const uint4*)vp; v1 = *(const uint4*)(vp + 8);
        }
      }

      if (kv0 <= wq0 + 15) {
        const int cb = cur * 8192;
        bf16x8 kf[2][4];
#pragma unroll
        for (int ks = 0; ks < 2; ks++)
#pragma unroll
          for (int nt = 0; nt < 4; nt++)
            kf[ks][nt] = *(const bf16x8*)(kbp + cb + krK[ks] + nt * 2048);

        f32x4 sacc[4] = {};
#pragma unroll
        for (int nt = 0; nt < 4; nt++) {
          sacc[nt] = MFMA16(kf[0][nt], qf0, sacc[nt]);
          sacc[nt] = MFMA16(kf[1][nt], qf1, sacc[nt]);
        }

        const bool domask = (kv0 + 63 > wq0);
        const int md = wq0 + l15 - kv0 - kvb;
        unsigned W[4][2];
#pragma unroll
        for (int nt = 0; nt < 4; nt++) {
          f32x4 pv;
#pragma unroll
          for (int r = 0; r < 4; r++) pv[r] = __builtin_exp2f(sacc[nt][r]);
          if (domask) {
#pragma unroll
            for (int r = 0; r < 4; r++)
              if (nt * 16 + r > md) pv[r] = 0.f;
          }
          W[nt][0] = cvtpk_bf16(pv[0], pv[1]);
          W[nt][1] = cvtpk_bf16(pv[2], pv[3]);
        }

#pragma unroll
        for (int ks = 0; ks < 2; ks++) {
          unsigned a0 = W[2 * ks][0], b0 = W[2 * ks + 1][0];
          unsigned a1 = W[2 * ks][1], b1 = W[2 * ks + 1][1];
          asm("v_permlane32_swap_b32 %0, %1" : "+v"(a0), "+v"(b0));
          asm("v_permlane32_swap_b32 %0, %1" : "+v"(a1), "+v"(b1));
          union { unsigned u[4]; bf16x8 v; } pk;
          pk.u[0] = a0; pk.u[1] = a1; pk.u[2] = b0; pk.u[3] = b1;
          bf16x8 pf = pk.v;

          bf16x8 vf[4];
#pragma unroll
          for (int nt = 0; nt < 4; nt++)
            vf[nt] = *(const bf16x8*)(vbp + cb + krV[ks] + nt * 2048);
          accs = MFMA16(pf, ones, accs);
#pragma unroll
          for (int nt = 0; nt < 4; nt++)
            acc[nt] = MFMA16(pf, vf[nt], acc[nt]);
        }
      }

      __syncthreads();
    }

    __bf16* op = O + ((size_t)(b * S_LEN + wq0 + quad * 4)) * HID + h * HD;
    float inv[4];
#pragma unroll
    for (int r = 0; r < 4; r++) inv[r] = 1.f / accs[r];
#pragma unroll
    for (int nt = 0; nt < 4; nt++)
#pragma unroll
      for (int r = 0; r < 4; r++)
        op[(size_t)r * HID + nt * 16 + l15] = (__bf16)(acc[nt][r] * inv[r]);
  }
}

extern "C" void kernel_launch(void* const* d_in, const int* in_sizes, int n_in,
                              void* d_out, int out_size, void* d_ws, size_t ws_size,
                              hipStream_t stream) {
  (void)in_sizes; (void)n_in; (void)out_size; (void)ws_size;
  const float* x  = (const float*)d_in[0];
  const float* fr = (const float*)d_in[1];
  const float* wq = (const float*)d_in[3];
  const float* bq = (const float*)d_in[4];
  const float* wk = (const float*)d_in[5];
  const float* bk = (const float*)d_in[6];
  const float* wv = (const float*)d_in[7];
  const float* bv = (const float*)d_in[8];
  const float* wo = (const float*)d_in[9];
  const float* bo = (const float*)d_in[10];
  float* out = (float*)d_out;
  char* ws = (char*)d_ws;

  __bf16* xb  = (__bf16*)(ws);
  __bf16* wqb = (__bf16*)(ws + ((size_t)16 << 20));
  __bf16* wkb = (__bf16*)(ws + ((size_t)24 << 20));
  __bf16* wvb = (__bf16*)(ws + ((size_t)26 << 20));
  __bf16* wob = (__bf16*)(ws + ((size_t)28 << 20));
  __bf16* Qb  = (__bf16*)(ws + ((size_t)36 << 20));
  __bf16* Kb  = (__bf16*)(ws + ((size_t)52 << 20));
  __bf16* Vtb = (__bf16*)(ws + ((size_t)60 << 20));
  __bf16* Ab  = (__bf16*)(ws + ((size_t)64 << 20));

  cast_all_k<<<18432, 256, 0, stream>>>(x, wq, wk, wv, wo, xb, wqb, wkb, wvb, wob);

  gemm_qkv_k<<<dim3(32, 24), 256, 0, stream>>>(xb, wqb, wkb, wvb, bq, bk, bv, fr, Qb, Kb, Vtb);

  flash_k<<<dim3(64, 16), 256, 0, stream>>>(Qb, Kb, Vtb, fr, Ab);

  gemm_out_k<<<dim3(32, 16), 256, 0, stream>>>(Ab, wob, bo, out);
}

// Round 8
// 308.322 us; speedup vs baseline: 1.2079x; 1.0024x over previous
//
#include <hip/hip_runtime.h>

#define S_LEN 2048
#define HID   2048
#define NQH   32
#define NKV   8
#define HD    64

#define BM 128
#define BN 128
#define BK 32

typedef __bf16 bf16x8 __attribute__((ext_vector_type(8)));
typedef __bf16 bf16x4 __attribute__((ext_vector_type(4)));
typedef float  f32x4  __attribute__((ext_vector_type(4)));

#define MFMA16(a, b, c) __builtin_amdgcn_mfma_f32_16x16x32_bf16(a, b, c, 0, 0, 0)

__device__ __forceinline__ void async_copy16(const void* g, void* l) {
  __builtin_amdgcn_global_load_lds(
      (const __attribute__((address_space(1))) unsigned int*)g,
      (__attribute__((address_space(3))) unsigned int*)l, 16, 0, 0);
}

__device__ __forceinline__ unsigned cvtpk_bf16(float lo, float hi) {
  unsigned r;
  asm("v_cvt_pk_bf16_f32 %0, %1, %2" : "=v"(r) : "v"(lo), "v"(hi));
  return r;
}

// ---------------- fused f32 -> bf16 cast of x + all weights ----------------
__global__ void cast_all_k(const float* __restrict__ x,  const float* __restrict__ wq,
                           const float* __restrict__ wk, const float* __restrict__ wv,
                           const float* __restrict__ wo,
                           __bf16* __restrict__ xb,  __bf16* __restrict__ wqb,
                           __bf16* __restrict__ wkb, __bf16* __restrict__ wvb,
                           __bf16* __restrict__ wob) {
  int bid = blockIdx.x;
  const float* in; __bf16* out; int base;
  if (bid < 8192)       { in = x;  out = xb;  base = bid; }
  else if (bid < 12288) { in = wq; out = wqb; base = bid - 8192; }
  else if (bid < 13312) { in = wk; out = wkb; base = bid - 12288; }
  else if (bid < 14336) { in = wv; out = wvb; base = bid - 13312; }
  else                  { in = wo; out = wob; base = bid - 14336; }
  int i = (base * 256 + threadIdx.x) * 4;
  float4 v = *(const float4*)(in + i);
  bf16x4 o;
  o[0] = (__bf16)v.x; o[1] = (__bf16)v.y; o[2] = (__bf16)v.z; o[3] = (__bf16)v.w;
  *(bf16x4*)(out + i) = o;
}

// ---------------- 128x128 BK=32 GEMM core, 3-stage counted-vmcnt pipeline ----------------
__device__ __forceinline__ void gemm_pipe(const __bf16* __restrict__ A,
                                          const __bf16* __restrict__ B,
                                          int m0, int n0, int K,
                                          __bf16 (&As)[3][BM][BK],
                                          __bf16 (&Bs)[3][BN][BK],
                                          f32x4 (&acc)[4][4]) {
  const int tid = threadIdx.x, wave = tid >> 6, lane = tid & 63;
  const int l15 = lane & 15, quad = lane >> 4;
  const int wr = wave >> 1, wc = wave & 1;

  const int srow   = tid >> 2;
  const int schunk = (tid & 3) ^ ((tid >> 3) & 3);
  const __bf16* ga = A + (size_t)(m0 + srow) * K + schunk * 8;
  const __bf16* gb = B + (size_t)(n0 + srow) * K + schunk * 8;

  const int co = (quad ^ ((l15 >> 1) & 3)) * 8;

  const int NT = K / BK;

#define STAGE(st, kt) do {                                              \
    async_copy16(ga + (kt),                  &As[st][wave * 16][0]);    \
    async_copy16(ga + (kt) + (size_t)64 * K, &As[st][64 + wave * 16][0]); \
    async_copy16(gb + (kt),                  &Bs[st][wave * 16][0]);    \
    async_copy16(gb + (kt) + (size_t)64 * K, &Bs[st][64 + wave * 16][0]); \
  } while (0)

  STAGE(0, 0);
  STAGE(1, BK);

  int s = 0;
#pragma unroll 1
  for (int t = 0; t < NT; t++) {
    if (t + 1 < NT) asm volatile("s_waitcnt vmcnt(4)" ::: "memory");
    else            asm volatile("s_waitcnt vmcnt(0)" ::: "memory");
    __builtin_amdgcn_s_barrier();
    asm volatile("" ::: "memory");

    if (t + 2 < NT) {
      int s2 = s + 2; if (s2 >= 3) s2 -= 3;
      STAGE(s2, (t + 2) * BK);
    }

    const __bf16* a0 = &As[s][wr * 64][0];
    const __bf16* b0 = &Bs[s][wc * 64][0];
    bf16x8 af[4], bfr[4];
#pragma unroll
    for (int mt = 0; mt < 4; mt++)
      af[mt] = *(const bf16x8*)(a0 + (mt * 16 + l15) * BK + co);
#pragma unroll
    for (int nt = 0; nt < 4; nt++)
      bfr[nt] = *(const bf16x8*)(b0 + (nt * 16 + l15) * BK + co);

    __builtin_amdgcn_s_setprio(1);
#pragma unroll
    for (int mt = 0; mt < 4; mt++)
#pragma unroll
      for (int nt = 0; nt < 4; nt++)
        acc[mt][nt] = MFMA16(af[mt], bfr[nt], acc[mt][nt]);
    __builtin_amdgcn_s_setprio(0);

    s = s + 1; if (s >= 3) s -= 3;
  }
#undef STAGE
}

// fused QKV projection + RoPE(K) + V transpose. grid (32, 24), 256 thr.
__global__ __launch_bounds__(256, 3) void gemm_qkv_k(const __bf16* __restrict__ xb,
    const __bf16* __restrict__ wqb, const __bf16* __restrict__ wkb, const __bf16* __restrict__ wvb,
    const float* __restrict__ bq, const float* __restrict__ bk, const float* __restrict__ bv,
    const float* __restrict__ fr,
    __bf16* __restrict__ Qb, __bf16* __restrict__ Kb, __bf16* __restrict__ Vt) {
  __shared__ __align__(16) __bf16 As[3][BM][BK];
  __shared__ __align__(16) __bf16 Bs[3][BN][BK];
  const int by = blockIdx.y;
  const int m0 = blockIdx.x * BM;
  const __bf16* B; const float* bias; int n0;
  int mode;  // 0 = plain Q, 1 = ropeK, 2 = vtrans
  if (by < 16)      { B = wqb; bias = bq; n0 = by * 128;        mode = 0; }
  else if (by < 20) { B = wkb; bias = bk; n0 = (by - 16) * 128; mode = 1; }
  else              { B = wvb; bias = bv; n0 = (by - 20) * 128; mode = 2; }

  f32x4 acc[4][4] = {};
  gemm_pipe(xb, B, m0, n0, HID, As, Bs, acc);

  const int tid = threadIdx.x, wave = tid >> 6, lane = tid & 63;
  const int l15 = lane & 15, quad = lane >> 4;
  const int wr = wave >> 1, wc = wave & 1;

  if (mode == 2) {
#pragma unroll
    for (int nt = 0; nt < 4; nt++) {
      int col = n0 + wc * 64 + nt * 16 + l15;       // 0..511
      int g = col >> 6, d = col & 63;
      float bv2 = bias[col];
#pragma unroll
      for (int mt = 0; mt < 4; mt++) {
        int row = m0 + wr * 64 + mt * 16 + quad * 4;
        int b = row >> 11, sI = row & 2047;
        bf16x4 o;
#pragma unroll
        for (int r = 0; r < 4; r++) o[r] = (__bf16)(acc[mt][nt][r] + bv2);
        *(bf16x4*)(Vt + (((size_t)(b * NKV + g) * HD + d)) * S_LEN + sI) = o;
      }
    }
  } else if (mode == 0) {
#pragma unroll
    for (int nt = 0; nt < 4; nt++) {
      int col = n0 + wc * 64 + nt * 16 + l15;
      float bv2 = bias[col];
#pragma unroll
      for (int mt = 0; mt < 4; mt++) {
        int row = m0 + wr * 64 + mt * 16 + quad * 4;
#pragma unroll
        for (int r = 0; r < 4; r++)
          Qb[(size_t)(row + r) * HID + col] = (__bf16)(acc[mt][nt][r] + bv2);
      }
    }
  } else {
    const int dpar = l15 & 1;
#pragma unroll
    for (int nt = 0; nt < 4; nt++) {
      int col = n0 + wc * 64 + nt * 16 + l15;
      int d = col & 63;
      float bv2 = bias[col];
#pragma unroll
      for (int mt = 0; mt < 4; mt++) {
        int row = m0 + wr * 64 + mt * 16 + quad * 4;
        int sI = row & 2047;
#pragma unroll
        for (int r = 0; r < 4; r++) {
          float v = acc[mt][nt][r] + bv2;
          float p = __shfl_xor(v, 1, 64);
          float f = fr[(size_t)(sI + r) * HD + d];
          float fp = __shfl_xor(f, 1, 64);
          float o = dpar ? (p * f + v * fp) : (v * f - p * fp);
          Kb[(size_t)(row + r) * 512 + col] = (__bf16)o;
        }
      }
    }
  }
}

// output projection: grid (32, 16) = 512 blocks
__global__ __launch_bounds__(256, 3) void gemm_out_k(const __bf16* __restrict__ A,
    const __bf16* __restrict__ Bw, const float* __restrict__ bias, float* __restrict__ C) {
  __shared__ __align__(16) __bf16 As[3][BM][BK];
  __shared__ __align__(16) __bf16 Bs[3][BN][BK];
  const int m0 = blockIdx.x * BM, n0 = blockIdx.y * BN;
  f32x4 acc[4][4] = {};
  gemm_pipe(A, Bw, m0, n0, HID, As, Bs, acc);
  const int tid = threadIdx.x, wave = tid >> 6, lane = tid & 63;
  const int l15 = lane & 15, quad = lane >> 4;
  const int wr = wave >> 1, wc = wave & 1;
#pragma unroll
  for (int nt = 0; nt < 4; nt++) {
    int col = n0 + wc * 64 + nt * 16 + l15;
    float bv = bias[col];
#pragma unroll
    for (int mt = 0; mt < 4; mt++) {
      int row = m0 + wr * 64 + mt * 16 + quad * 4;
#pragma unroll
      for (int r = 0; r < 4; r++)
        C[(size_t)(row + r) * HID + col] = acc[mt][nt][r] + bv;
    }
  }
}

// RoPE a bf16x8 (pairs 2j,2j+1 adjacent) with contiguous f32 freqs, fused scale.
__device__ __forceinline__ void rope8(bf16x8& q, const float* f, float sc) {
  float4 fa = *(const float4*)f;
  float4 fb = *(const float4*)(f + 4);
  float e, o;
  e = (float)q[0]; o = (float)q[1];
  q[0] = (__bf16)((e * fa.x - o * fa.y) * sc);
  q[1] = (__bf16)((e * fa.y + o * fa.x) * sc);
  e = (float)q[2]; o = (float)q[3];
  q[2] = (__bf16)((e * fa.z - o * fa.w) * sc);
  q[3] = (__bf16)((e * fa.w + o * fa.z) * sc);
  e = (float)q[4]; o = (float)q[5];
  q[4] = (__bf16)((e * fb.x - o * fb.y) * sc);
  q[5] = (__bf16)((e * fb.y + o * fb.x) * sc);
  e = (float)q[6]; o = (float)q[7];
  q[6] = (__bf16)((e * fb.z - o * fb.w) * sc);
  q[7] = (__bf16)((e * fb.w + o * fb.z) * sc);
}

// ---------------- Flash attention v9: 32 q-rows/wave (K/V LDS reads amortized 2x) ----------------
// 128-row q-tiles (16 tiles). Block y handles pair (y, 15-y): NT = (2y+2)+(32-2y) = 34
// kv-iters for every block. 4 waves; each wave owns TWO 16-row q-groups (A: wq0..+16,
// B: wq0+64..+16). kf/vf read ONCE per iter, feed both groups -> LDS traffic per
// q-row halved vs v8 (the v8 limiter: ~52us of pure LDS-pipe time).
// Group A is inactive only on each half's last kv tile; A masks at t==2qt, B at NT-1.
// All v8 machinery (sigma-permuted kf, cvt_pk+permlane32 P assembly, no-max exp2
// softmax, double-buffered K/V, one barrier/iter) unchanged per group.
__global__ __launch_bounds__(256, 2) void flash_k(const __bf16* __restrict__ Q,
                                                  const __bf16* __restrict__ K,
                                                  const __bf16* __restrict__ Vt,
                                                  const float* __restrict__ fr,
                                                  __bf16* __restrict__ O) {
  __shared__ __align__(64) __bf16 Ksm[2][64][64];    // [buf][kv][d] swizzled (key=row&7)
  __shared__ __align__(64) __bf16 Vsm[2][64][64];    // [buf][d][kv] swizzled
  const int tid = threadIdx.x;
  const int wave = tid >> 6, lane = tid & 63;
  const int l15 = lane & 15, quad = lane >> 4;
  const int bh = blockIdx.x;
  const int b = bh >> 5, h = bh & 31, g = h >> 2;

  const int srow = tid >> 2, sc = (tid & 3) * 16;
  const int r7 = srow & 7;
  const int w0 = (((sc >> 3))     ^ r7) * 8;
  const int w1 = (((sc >> 3) + 1) ^ r7) * 8;

  const char* kbp = (const char*)&Ksm[0][0][0];
  const char* vbp = (const char*)&Vsm[0][0][0];

  const int x7  = l15 & 7;
  const int sig = 8 * ((l15 >> 2) & 1) + 4 * (l15 >> 3) + (l15 & 3);
  const int s7  = sig & 7;
  int krK[2], krV[2];
#pragma unroll
  for (int ks = 0; ks < 2; ks++) {
    krK[ks] = sig * 128 + (((ks * 4 + quad) ^ s7) * 16);
    krV[ks] = l15 * 128 + (((ks * 4 + quad) ^ x7) * 16);
  }
  const int kvb = 8 * (quad & 1) + 4 * (quad >> 1);

  bf16x8 ones;
#pragma unroll
  for (int j = 0; j < 8; j++) ones[j] = (__bf16)1.0f;

  const __bf16* kbase = K + ((size_t)b * S_LEN + srow) * (NKV * HD) + g * HD + sc;
  const __bf16* vbase = Vt + (((size_t)b * NKV + g) * HD + srow) * S_LEN + sc;
  const float QSC = 0.125f * 1.44269504f;   // 1/sqrt(64) * log2(e)
  const int KSTEP = 64 * NKV * HD;

#pragma unroll 1
  for (int half = 0; half < 2; half++) {
    const int qt = half ? (15 - (int)blockIdx.y) : (int)blockIdx.y;
    const int NT = 2 * qt + 2;                 // kv tiles for this q-tile
    const int wq0 = qt * 128 + wave * 16;      // group A rows; group B = +64

    const __bf16* qpA = Q + ((size_t)(b * S_LEN + wq0 + l15)) * HID + h * HD + quad * 8;
    const __bf16* qpB = qpA + (size_t)64 * HID;
    bf16x8 qfA0 = *(const bf16x8*)qpA;
    bf16x8 qfA1 = *(const bf16x8*)(qpA + 32);
    bf16x8 qfB0 = *(const bf16x8*)qpB;
    bf16x8 qfB1 = *(const bf16x8*)(qpB + 32);
    const float* fqA = fr + (size_t)(wq0 + l15) * HD + quad * 8;
    const float* fqB = fqA + (size_t)64 * HD;
    rope8(qfA0, fqA, QSC);
    rope8(qfA1, fqA + 32, QSC);
    rope8(qfB0, fqB, QSC);
    rope8(qfB1, fqB + 32, QSC);

    f32x4 accA[4] = {}, accB[4] = {};
    f32x4 accsA = {}, accsB = {};

    const __bf16* kp = kbase;
    const __bf16* vp = vbase;
    uint4 k0 = *(const uint4*)kp, k1 = *(const uint4*)(kp + 8);
    uint4 v0 = *(const uint4*)vp, v1 = *(const uint4*)(vp + 8);
    *(uint4*)&Ksm[0][srow][w0] = k0;
    *(uint4*)&Ksm[0][srow][w1] = k1;
    *(uint4*)&Vsm[0][srow][w0] = v0;
    *(uint4*)&Vsm[0][srow][w1] = v1;
    // NT >= 2 always: prefetch tile 1
    kp += KSTEP;  vp += 64;
    k0 = *(const uint4*)kp; k1 = *(const uint4*)(kp + 8);
    v0 = *(const uint4*)vp; v1 = *(const uint4*)(vp + 8);
    __syncthreads();

#pragma unroll 1
    for (int t = 0; t < NT; t++) {
      const int cur = t & 1;
      const int kv0 = t * 64;

      if (t + 1 < NT) {
        *(uint4*)&Ksm[cur ^ 1][srow][w0] = k0;
        *(uint4*)&Ksm[cur ^ 1][srow][w1] = k1;
        *(uint4*)&Vsm[cur ^ 1][srow][w0] = v0;
        *(uint4*)&Vsm[cur ^ 1][srow][w1] = v1;
        if (t + 2 < NT) {
          kp += KSTEP;  vp += 64;
          k0 = *(const uint4*)kp; k1 = *(const uint4*)(kp + 8);
          v0 = *(const uint4*)vp; v1 = *(const uint4*)(vp + 8);
        }
      }

      const bool actA = (kv0 <= wq0 + 15);   // group A not fully masked (uniform/wave)
      const int cb = cur * 8192;

      bf16x8 kf[2][4];
#pragma unroll
      for (int ks = 0; ks < 2; ks++)
#pragma unroll
        for (int nt = 0; nt < 4; nt++)
          kf[ks][nt] = *(const bf16x8*)(kbp + cb + krK[ks] + nt * 2048);

      // ---- group B scores (always active; B q-rows = wq0+64..) ----
      unsigned WB[4][2];
      {
        f32x4 sacc[4] = {};
#pragma unroll
        for (int nt = 0; nt < 4; nt++) {
          sacc[nt] = MFMA16(kf[0][nt], qfB0, sacc[nt]);
          sacc[nt] = MFMA16(kf[1][nt], qfB1, sacc[nt]);
        }
        const int wq0B = wq0 + 64;
        const bool domask = (kv0 + 63 > wq0B);
        const int md = wq0B + l15 - kv0 - kvb;
#pragma unroll
        for (int nt = 0; nt < 4; nt++) {
          f32x4 pv;
#pragma unroll
          for (int r = 0; r < 4; r++) pv[r] = __builtin_exp2f(sacc[nt][r]);
          if (domask) {
#pragma unroll
            for (int r = 0; r < 4; r++)
              if (nt * 16 + r > md) pv[r] = 0.f;
          }
          WB[nt][0] = cvtpk_bf16(pv[0], pv[1]);
          WB[nt][1] = cvtpk_bf16(pv[2], pv[3]);
        }
      }
      // ---- group A scores ----
      unsigned WA[4][2];
      if (actA) {
        f32x4 sacc[4] = {};
#pragma unroll
        for (int nt = 0; nt < 4; nt++) {
          sacc[nt] = MFMA16(kf[0][nt], qfA0, sacc[nt]);
          sacc[nt] = MFMA16(kf[1][nt], qfA1, sacc[nt]);
        }
        const bool domask = (kv0 + 63 > wq0);
        const int md = wq0 + l15 - kv0 - kvb;
#pragma unroll
        for (int nt = 0; nt < 4; nt++) {
          f32x4 pv;
#pragma unroll
          for (int r = 0; r < 4; r++) pv[r] = __builtin_exp2f(sacc[nt][r]);
          if (domask) {
#pragma unroll
            for (int r = 0; r < 4; r++)
              if (nt * 16 + r > md) pv[r] = 0.f;
          }
          WA[nt][0] = cvtpk_bf16(pv[0], pv[1]);
          WA[nt][1] = cvtpk_bf16(pv[2], pv[3]);
        }
      }

      // ---- PV for both groups; vf read once ----
#pragma unroll
      for (int ks = 0; ks < 2; ks++) {
        bf16x8 vf[4];
#pragma unroll
        for (int nt = 0; nt < 4; nt++)
          vf[nt] = *(const bf16x8*)(vbp + cb + krV[ks] + nt * 2048);

        {
          unsigned a0 = WB[2 * ks][0], b0 = WB[2 * ks + 1][0];
          unsigned a1 = WB[2 * ks][1], b1 = WB[2 * ks + 1][1];
          asm("v_permlane32_swap_b32 %0, %1" : "+v"(a0), "+v"(b0));
          asm("v_permlane32_swap_b32 %0, %1" : "+v"(a1), "+v"(b1));
          union { unsigned u[4]; bf16x8 v; } pk;
          pk.u[0] = a0; pk.u[1] = a1; pk.u[2] = b0; pk.u[3] = b1;
          bf16x8 pf = pk.v;
          accsB = MFMA16(pf, ones, accsB);
#pragma unroll
          for (int nt = 0; nt < 4; nt++)
            accB[nt] = MFMA16(pf, vf[nt], accB[nt]);
        }
        if (actA) {
          unsigned a0 = WA[2 * ks][0], b0 = WA[2 * ks + 1][0];
          unsigned a1 = WA[2 * ks][1], b1 = WA[2 * ks + 1][1];
          asm("v_permlane32_swap_b32 %0, %1" : "+v"(a0), "+v"(b0));
          asm("v_permlane32_swap_b32 %0, %1" : "+v"(a1), "+v"(b1));
          union { unsigned u[4]; bf16x8 v; } pk;
          pk.u[0] = a0; pk.u[1] = a1; pk.u[2] = b0; pk.u[3] = b1;
          bf16x8 pf = pk.v;
          accsA = MFMA16(pf, ones, accsA);
#pragma unroll
          for (int nt = 0; nt < 4; nt++)
            accA[nt] = MFMA16(pf, vf[nt], accA[nt]);
        }
      }

      __syncthreads();
    }

    // epilogue for both groups (rows quad*4+r; group B rows +64)
    __bf16* opA = O + ((size_t)(b * S_LEN + wq0 + quad * 4)) * HID + h * HD;
    __bf16* opB = opA + (size_t)64 * HID;
    float invA[4], invB[4];
#pragma unroll
    for (int r = 0; r < 4; r++) { invA[r] = 1.f / accsA[r]; invB[r] = 1.f / accsB[r]; }
#pragma unroll
    for (int nt = 0; nt < 4; nt++)
#pragma unroll
      for (int r = 0; r < 4; r++) {
        opA[(size_t)r * HID + nt * 16 + l15] = (__bf16)(accA[nt][r] * invA[r]);
        opB[(size_t)r * HID + nt * 16 + l15] = (__bf16)(accB[nt][r] * invB[r]);
      }
  }
}

extern "C" void kernel_launch(void* const* d_in, const int* in_sizes, int n_in,
                              void* d_out, int out_size, void* d_ws, size_t ws_size,
                              hipStream_t stream) {
  (void)in_sizes; (void)n_in; (void)out_size; (void)ws_size;
  const float* x  = (const float*)d_in[0];
  const float* fr = (const float*)d_in[1];
  const float* wq = (const float*)d_in[3];
  const float* bq = (const float*)d_in[4];
  const float* wk = (const float*)d_in[5];
  const float* bk = (const float*)d_in[6];
  const float* wv = (const float*)d_in[7];
  const float* bv = (const float*)d_in[8];
  const float* wo = (const float*)d_in[9];
  const float* bo = (const float*)d_in[10];
  float* out = (float*)d_out;
  char* ws = (char*)d_ws;

  __bf16* xb  = (__bf16*)(ws);
  __bf16* wqb = (__bf16*)(ws + ((size_t)16 << 20));
  __bf16* wkb = (__bf16*)(ws + ((size_t)24 << 20));
  __bf16* wvb = (__bf16*)(ws + ((size_t)26 << 20));
  __bf16* wob = (__bf16*)(ws + ((size_t)28 << 20));
  __bf16* Qb  = (__bf16*)(ws + ((size_t)36 << 20));
  __bf16* Kb  = (__bf16*)(ws + ((size_t)52 << 20));
  __bf16* Vtb = (__bf16*)(ws + ((size_t)60 << 20));
  __bf16* Ab  = (__bf16*)(ws + ((size_t)64 << 20));

  cast_all_k<<<18432, 256, 0, stream>>>(x, wq, wk, wv, wo, xb, wqb, wkb, wvb, wob);

  gemm_qkv_k<<<dim3(32, 24), 256, 0, stream>>>(xb, wqb, wkb, wvb, bq, bk, bv, fr, Qb, Kb, Vtb);

  flash_k<<<dim3(64, 8), 256, 0, stream>>>(Qb, Kb, Vtb, fr, Ab);

  gemm_out_k<<<dim3(32, 16), 256, 0, stream>>>(Ab, wob, bo, out);
}

// Round 9
// 293.829 us; speedup vs baseline: 1.2675x; 1.0493x over previous
//
#include <hip/hip_runtime.h>

#define S_LEN 2048
#define HID   2048
#define NQH   32
#define NKV   8
#define HD    64

#define BM 128
#define BN 128
#define BK 32

typedef __bf16 bf16x8 __attribute__((ext_vector_type(8)));
typedef __bf16 bf16x4 __attribute__((ext_vector_type(4)));
typedef float  f32x4  __attribute__((ext_vector_type(4)));

#define MFMA16(a, b, c) __builtin_amdgcn_mfma_f32_16x16x32_bf16(a, b, c, 0, 0, 0)

__device__ __forceinline__ void async_copy16(const void* g, void* l) {
  __builtin_amdgcn_global_load_lds(
      (const __attribute__((address_space(1))) unsigned int*)g,
      (__attribute__((address_space(3))) unsigned int*)l, 16, 0, 0);
}

__device__ __forceinline__ unsigned cvtpk_bf16(float lo, float hi) {
  unsigned r;
  asm("v_cvt_pk_bf16_f32 %0, %1, %2" : "=v"(r) : "v"(lo), "v"(hi));
  return r;
}

// raw v_exp_f32: no denormal-guard expansion (scores are O(1); FTZ on large-neg
// is exactly softmax's zero). ~1 ulp, invisible at bf16 output precision.
__device__ __forceinline__ float exp2_raw(float x) {
  float r;
  asm("v_exp_f32 %0, %1" : "=v"(r) : "v"(x));
  return r;
}
__device__ __forceinline__ float rcp_raw(float x) {
  float r;
  asm("v_rcp_f32 %0, %1" : "=v"(r) : "v"(x));
  return r;
}

// ---------------- fused f32 -> bf16 cast of x + all weights ----------------
__global__ void cast_all_k(const float* __restrict__ x,  const float* __restrict__ wq,
                           const float* __restrict__ wk, const float* __restrict__ wv,
                           const float* __restrict__ wo,
                           __bf16* __restrict__ xb,  __bf16* __restrict__ wqb,
                           __bf16* __restrict__ wkb, __bf16* __restrict__ wvb,
                           __bf16* __restrict__ wob) {
  int bid = blockIdx.x;
  const float* in; __bf16* out; int base;
  if (bid < 8192)       { in = x;  out = xb;  base = bid; }
  else if (bid < 12288) { in = wq; out = wqb; base = bid - 8192; }
  else if (bid < 13312) { in = wk; out = wkb; base = bid - 12288; }
  else if (bid < 14336) { in = wv; out = wvb; base = bid - 13312; }
  else                  { in = wo; out = wob; base = bid - 14336; }
  int i = (base * 256 + threadIdx.x) * 4;
  float4 v = *(const float4*)(in + i);
  bf16x4 o;
  o[0] = (__bf16)v.x; o[1] = (__bf16)v.y; o[2] = (__bf16)v.z; o[3] = (__bf16)v.w;
  *(bf16x4*)(out + i) = o;
}

// ---------------- 128x128 BK=32 GEMM core, 3-stage counted-vmcnt pipeline ----------------
__device__ __forceinline__ void gemm_pipe(const __bf16* __restrict__ A,
                                          const __bf16* __restrict__ B,
                                          int m0, int n0, int K,
                                          __bf16 (&As)[3][BM][BK],
                                          __bf16 (&Bs)[3][BN][BK],
                                          f32x4 (&acc)[4][4]) {
  const int tid = threadIdx.x, wave = tid >> 6, lane = tid & 63;
  const int l15 = lane & 15, quad = lane >> 4;
  const int wr = wave >> 1, wc = wave & 1;

  const int srow   = tid >> 2;
  const int schunk = (tid & 3) ^ ((tid >> 3) & 3);
  const __bf16* ga = A + (size_t)(m0 + srow) * K + schunk * 8;
  const __bf16* gb = B + (size_t)(n0 + srow) * K + schunk * 8;

  const int co = (quad ^ ((l15 >> 1) & 3)) * 8;

  const int NT = K / BK;

#define STAGE(st, kt) do {                                              \
    async_copy16(ga + (kt),                  &As[st][wave * 16][0]);    \
    async_copy16(ga + (kt) + (size_t)64 * K, &As[st][64 + wave * 16][0]); \
    async_copy16(gb + (kt),                  &Bs[st][wave * 16][0]);    \
    async_copy16(gb + (kt) + (size_t)64 * K, &Bs[st][64 + wave * 16][0]); \
  } while (0)

  STAGE(0, 0);
  STAGE(1, BK);

  int s = 0;
#pragma unroll 1
  for (int t = 0; t < NT; t++) {
    if (t + 1 < NT) asm volatile("s_waitcnt vmcnt(4)" ::: "memory");
    else            asm volatile("s_waitcnt vmcnt(0)" ::: "memory");
    __builtin_amdgcn_s_barrier();
    asm volatile("" ::: "memory");

    if (t + 2 < NT) {
      int s2 = s + 2; if (s2 >= 3) s2 -= 3;
      STAGE(s2, (t + 2) * BK);
    }

    const __bf16* a0 = &As[s][wr * 64][0];
    const __bf16* b0 = &Bs[s][wc * 64][0];
    bf16x8 af[4], bfr[4];
#pragma unroll
    for (int mt = 0; mt < 4; mt++)
      af[mt] = *(const bf16x8*)(a0 + (mt * 16 + l15) * BK + co);
#pragma unroll
    for (int nt = 0; nt < 4; nt++)
      bfr[nt] = *(const bf16x8*)(b0 + (nt * 16 + l15) * BK + co);

    __builtin_amdgcn_s_setprio(1);
#pragma unroll
    for (int mt = 0; mt < 4; mt++)
#pragma unroll
      for (int nt = 0; nt < 4; nt++)
        acc[mt][nt] = MFMA16(af[mt], bfr[nt], acc[mt][nt]);
    __builtin_amdgcn_s_setprio(0);

    s = s + 1; if (s >= 3) s -= 3;
  }
#undef STAGE
}

// fused QKV projection + RoPE(K) + V transpose. grid (32, 24), 256 thr.
__global__ __launch_bounds__(256, 3) void gemm_qkv_k(const __bf16* __restrict__ xb,
    const __bf16* __restrict__ wqb, const __bf16* __restrict__ wkb, const __bf16* __restrict__ wvb,
    const float* __restrict__ bq, const float* __restrict__ bk, const float* __restrict__ bv,
    const float* __restrict__ fr,
    __bf16* __restrict__ Qb, __bf16* __restrict__ Kb, __bf16* __restrict__ Vt) {
  __shared__ __align__(16) __bf16 As[3][BM][BK];
  __shared__ __align__(16) __bf16 Bs[3][BN][BK];
  const int by = blockIdx.y;
  const int m0 = blockIdx.x * BM;
  const __bf16* B; const float* bias; int n0;
  int mode;  // 0 = plain Q, 1 = ropeK, 2 = vtrans
  if (by < 16)      { B = wqb; bias = bq; n0 = by * 128;        mode = 0; }
  else if (by < 20) { B = wkb; bias = bk; n0 = (by - 16) * 128; mode = 1; }
  else              { B = wvb; bias = bv; n0 = (by - 20) * 128; mode = 2; }

  f32x4 acc[4][4] = {};
  gemm_pipe(xb, B, m0, n0, HID, As, Bs, acc);

  const int tid = threadIdx.x, wave = tid >> 6, lane = tid & 63;
  const int l15 = lane & 15, quad = lane >> 4;
  const int wr = wave >> 1, wc = wave & 1;

  if (mode == 2) {
#pragma unroll
    for (int nt = 0; nt < 4; nt++) {
      int col = n0 + wc * 64 + nt * 16 + l15;       // 0..511
      int g = col >> 6, d = col & 63;
      float bv2 = bias[col];
#pragma unroll
      for (int mt = 0; mt < 4; mt++) {
        int row = m0 + wr * 64 + mt * 16 + quad * 4;
        int b = row >> 11, sI = row & 2047;
        bf16x4 o;
#pragma unroll
        for (int r = 0; r < 4; r++) o[r] = (__bf16)(acc[mt][nt][r] + bv2);
        *(bf16x4*)(Vt + (((size_t)(b * NKV + g) * HD + d)) * S_LEN + sI) = o;
      }
    }
  } else if (mode == 0) {
#pragma unroll
    for (int nt = 0; nt < 4; nt++) {
      int col = n0 + wc * 64 + nt * 16 + l15;
      float bv2 = bias[col];
#pragma unroll
      for (int mt = 0; mt < 4; mt++) {
        int row = m0 + wr * 64 + mt * 16 + quad * 4;
#pragma unroll
        for (int r = 0; r < 4; r++)
          Qb[(size_t)(row + r) * HID + col] = (__bf16)(acc[mt][nt][r] + bv2);
      }
    }
  } else {
    const int dpar = l15 & 1;
#pragma unroll
    for (int nt = 0; nt < 4; nt++) {
      int col = n0 + wc * 64 + nt * 16 + l15;
      int d = col & 63;
      float bv2 = bias[col];
#pragma unroll
      for (int mt = 0; mt < 4; mt++) {
        int row = m0 + wr * 64 + mt * 16 + quad * 4;
        int sI = row & 2047;
#pragma unroll
        for (int r = 0; r < 4; r++) {
          float v = acc[mt][nt][r] + bv2;
          float p = __shfl_xor(v, 1, 64);
          float f = fr[(size_t)(sI + r) * HD + d];
          float fp = __shfl_xor(f, 1, 64);
          float o = dpar ? (p * f + v * fp) : (v * f - p * fp);
          Kb[(size_t)(row + r) * 512 + col] = (__bf16)o;
        }
      }
    }
  }
}

// output projection: grid (32, 16) = 512 blocks
__global__ __launch_bounds__(256, 3) void gemm_out_k(const __bf16* __restrict__ A,
    const __bf16* __restrict__ Bw, const float* __restrict__ bias, float* __restrict__ C) {
  __shared__ __align__(16) __bf16 As[3][BM][BK];
  __shared__ __align__(16) __bf16 Bs[3][BN][BK];
  const int m0 = blockIdx.x * BM, n0 = blockIdx.y * BN;
  f32x4 acc[4][4] = {};
  gemm_pipe(A, Bw, m0, n0, HID, As, Bs, acc);
  const int tid = threadIdx.x, wave = tid >> 6, lane = tid & 63;
  const int l15 = lane & 15, quad = lane >> 4;
  const int wr = wave >> 1, wc = wave & 1;
#pragma unroll
  for (int nt = 0; nt < 4; nt++) {
    int col = n0 + wc * 64 + nt * 16 + l15;
    float bv = bias[col];
#pragma unroll
    for (int mt = 0; mt < 4; mt++) {
      int row = m0 + wr * 64 + mt * 16 + quad * 4;
#pragma unroll
      for (int r = 0; r < 4; r++)
        C[(size_t)(row + r) * HID + col] = acc[mt][nt][r] + bv;
    }
  }
}

// RoPE a bf16x8 (pairs 2j,2j+1 adjacent) with contiguous f32 freqs, fused scale.
__device__ __forceinline__ void rope8(bf16x8& q, const float* f, float sc) {
  float4 fa = *(const float4*)f;
  float4 fb = *(const float4*)(f + 4);
  float e, o;
  e = (float)q[0]; o = (float)q[1];
  q[0] = (__bf16)((e * fa.x - o * fa.y) * sc);
  q[1] = (__bf16)((e * fa.y + o * fa.x) * sc);
  e = (float)q[2]; o = (float)q[3];
  q[2] = (__bf16)((e * fa.z - o * fa.w) * sc);
  q[3] = (__bf16)((e * fa.w + o * fa.z) * sc);
  e = (float)q[4]; o = (float)q[5];
  q[4] = (__bf16)((e * fb.x - o * fb.y) * sc);
  q[5] = (__bf16)((e * fb.y + o * fb.x) * sc);
  e = (float)q[6]; o = (float)q[7];
  q[6] = (__bf16)((e * fb.z - o * fb.w) * sc);
  q[7] = (__bf16)((e * fb.w + o * fb.z) * sc);
}

// ---------------- Flash attention v10: v9 + raw v_exp_f32 + setprio on MFMA ----------------
__global__ __launch_bounds__(256, 2) void flash_k(const __bf16* __restrict__ Q,
                                                  const __bf16* __restrict__ K,
                                                  const __bf16* __restrict__ Vt,
                                                  const float* __restrict__ fr,
                                                  __bf16* __restrict__ O) {
  __shared__ __align__(64) __bf16 Ksm[2][64][64];    // [buf][kv][d] swizzled (key=row&7)
  __shared__ __align__(64) __bf16 Vsm[2][64][64];    // [buf][d][kv] swizzled
  const int tid = threadIdx.x;
  const int wave = tid >> 6, lane = tid & 63;
  const int l15 = lane & 15, quad = lane >> 4;
  const int bh = blockIdx.x;
  const int b = bh >> 5, h = bh & 31, g = h >> 2;

  const int srow = tid >> 2, sc = (tid & 3) * 16;
  const int r7 = srow & 7;
  const int w0 = (((sc >> 3))     ^ r7) * 8;
  const int w1 = (((sc >> 3) + 1) ^ r7) * 8;

  const char* kbp = (const char*)&Ksm[0][0][0];
  const char* vbp = (const char*)&Vsm[0][0][0];

  const int x7  = l15 & 7;
  const int sig = 8 * ((l15 >> 2) & 1) + 4 * (l15 >> 3) + (l15 & 3);
  const int s7  = sig & 7;
  int krK[2], krV[2];
#pragma unroll
  for (int ks = 0; ks < 2; ks++) {
    krK[ks] = sig * 128 + (((ks * 4 + quad) ^ s7) * 16);
    krV[ks] = l15 * 128 + (((ks * 4 + quad) ^ x7) * 16);
  }
  const int kvb = 8 * (quad & 1) + 4 * (quad >> 1);

  bf16x8 ones;
#pragma unroll
  for (int j = 0; j < 8; j++) ones[j] = (__bf16)1.0f;

  const __bf16* kbase = K + ((size_t)b * S_LEN + srow) * (NKV * HD) + g * HD + sc;
  const __bf16* vbase = Vt + (((size_t)b * NKV + g) * HD + srow) * S_LEN + sc;
  const float QSC = 0.125f * 1.44269504f;   // 1/sqrt(64) * log2(e)
  const int KSTEP = 64 * NKV * HD;

#pragma unroll 1
  for (int half = 0; half < 2; half++) {
    const int qt = half ? (15 - (int)blockIdx.y) : (int)blockIdx.y;
    const int NT = 2 * qt + 2;                 // kv tiles for this q-tile
    const int wq0 = qt * 128 + wave * 16;      // group A rows; group B = +64

    const __bf16* qpA = Q + ((size_t)(b * S_LEN + wq0 + l15)) * HID + h * HD + quad * 8;
    const __bf16* qpB = qpA + (size_t)64 * HID;
    bf16x8 qfA0 = *(const bf16x8*)qpA;
    bf16x8 qfA1 = *(const bf16x8*)(qpA + 32);
    bf16x8 qfB0 = *(const bf16x8*)qpB;
    bf16x8 qfB1 = *(const bf16x8*)(qpB + 32);
    const float* fqA = fr + (size_t)(wq0 + l15) * HD + quad * 8;
    const float* fqB = fqA + (size_t)64 * HD;
    rope8(qfA0, fqA, QSC);
    rope8(qfA1, fqA + 32, QSC);
    rope8(qfB0, fqB, QSC);
    rope8(qfB1, fqB + 32, QSC);

    f32x4 accA[4] = {}, accB[4] = {};
    f32x4 accsA = {}, accsB = {};

    const __bf16* kp = kbase;
    const __bf16* vp = vbase;
    uint4 k0 = *(const uint4*)kp, k1 = *(const uint4*)(kp + 8);
    uint4 v0 = *(const uint4*)vp, v1 = *(const uint4*)(vp + 8);
    *(uint4*)&Ksm[0][srow][w0] = k0;
    *(uint4*)&Ksm[0][srow][w1] = k1;
    *(uint4*)&Vsm[0][srow][w0] = v0;
    *(uint4*)&Vsm[0][srow][w1] = v1;
    // NT >= 2 always: prefetch tile 1
    kp += KSTEP;  vp += 64;
    k0 = *(const uint4*)kp; k1 = *(const uint4*)(kp + 8);
    v0 = *(const uint4*)vp; v1 = *(const uint4*)(vp + 8);
    __syncthreads();

#pragma unroll 1
    for (int t = 0; t < NT; t++) {
      const int cur = t & 1;
      const int kv0 = t * 64;

      if (t + 1 < NT) {
        *(uint4*)&Ksm[cur ^ 1][srow][w0] = k0;
        *(uint4*)&Ksm[cur ^ 1][srow][w1] = k1;
        *(uint4*)&Vsm[cur ^ 1][srow][w0] = v0;
        *(uint4*)&Vsm[cur ^ 1][srow][w1] = v1;
        if (t + 2 < NT) {
          kp += KSTEP;  vp += 64;
          k0 = *(const uint4*)kp; k1 = *(const uint4*)(kp + 8);
          v0 = *(const uint4*)vp; v1 = *(const uint4*)(vp + 8);
        }
      }

      const bool actA = (kv0 <= wq0 + 15);   // group A not fully masked (uniform/wave)
      const int cb = cur * 8192;

      bf16x8 kf[2][4];
#pragma unroll
      for (int ks = 0; ks < 2; ks++)
#pragma unroll
        for (int nt = 0; nt < 4; nt++)
          kf[ks][nt] = *(const bf16x8*)(kbp + cb + krK[ks] + nt * 2048);

      // ---- group B scores (always active; B q-rows = wq0+64..) ----
      unsigned WB[4][2];
      {
        f32x4 sacc[4] = {};
        __builtin_amdgcn_s_setprio(1);
#pragma unroll
        for (int nt = 0; nt < 4; nt++) {
          sacc[nt] = MFMA16(kf[0][nt], qfB0, sacc[nt]);
          sacc[nt] = MFMA16(kf[1][nt], qfB1, sacc[nt]);
        }
        __builtin_amdgcn_s_setprio(0);
        const int wq0B = wq0 + 64;
        const bool domask = (kv0 + 63 > wq0B);
        const int md = wq0B + l15 - kv0 - kvb;
#pragma unroll
        for (int nt = 0; nt < 4; nt++) {
          f32x4 pv;
#pragma unroll
          for (int r = 0; r < 4; r++) pv[r] = exp2_raw(sacc[nt][r]);
          if (domask) {
#pragma unroll
            for (int r = 0; r < 4; r++)
              if (nt * 16 + r > md) pv[r] = 0.f;
          }
          WB[nt][0] = cvtpk_bf16(pv[0], pv[1]);
          WB[nt][1] = cvtpk_bf16(pv[2], pv[3]);
        }
      }
      // ---- group A scores ----
      unsigned WA[4][2];
      if (actA) {
        f32x4 sacc[4] = {};
        __builtin_amdgcn_s_setprio(1);
#pragma unroll
        for (int nt = 0; nt < 4; nt++) {
          sacc[nt] = MFMA16(kf[0][nt], qfA0, sacc[nt]);
          sacc[nt] = MFMA16(kf[1][nt], qfA1, sacc[nt]);
        }
        __builtin_amdgcn_s_setprio(0);
        const bool domask = (kv0 + 63 > wq0);
        const int md = wq0 + l15 - kv0 - kvb;
#pragma unroll
        for (int nt = 0; nt < 4; nt++) {
          f32x4 pv;
#pragma unroll
          for (int r = 0; r < 4; r++) pv[r] = exp2_raw(sacc[nt][r]);
          if (domask) {
#pragma unroll
            for (int r = 0; r < 4; r++)
              if (nt * 16 + r > md) pv[r] = 0.f;
          }
          WA[nt][0] = cvtpk_bf16(pv[0], pv[1]);
          WA[nt][1] = cvtpk_bf16(pv[2], pv[3]);
        }
      }

      // ---- PV for both groups; vf read once ----
#pragma unroll
      for (int ks = 0; ks < 2; ks++) {
        bf16x8 vf[4];
#pragma unroll
        for (int nt = 0; nt < 4; nt++)
          vf[nt] = *(const bf16x8*)(vbp + cb + krV[ks] + nt * 2048);

        {
          unsigned a0 = WB[2 * ks][0], b0 = WB[2 * ks + 1][0];
          unsigned a1 = WB[2 * ks][1], b1 = WB[2 * ks + 1][1];
          asm("v_permlane32_swap_b32 %0, %1" : "+v"(a0), "+v"(b0));
          asm("v_permlane32_swap_b32 %0, %1" : "+v"(a1), "+v"(b1));
          union { unsigned u[4]; bf16x8 v; } pk;
          pk.u[0] = a0; pk.u[1] = a1; pk.u[2] = b0; pk.u[3] = b1;
          bf16x8 pf = pk.v;
          __builtin_amdgcn_s_setprio(1);
          accsB = MFMA16(pf, ones, accsB);
#pragma unroll
          for (int nt = 0; nt < 4; nt++)
            accB[nt] = MFMA16(pf, vf[nt], accB[nt]);
          __builtin_amdgcn_s_setprio(0);
        }
        if (actA) {
          unsigned a0 = WA[2 * ks][0], b0 = WA[2 * ks + 1][0];
          unsigned a1 = WA[2 * ks][1], b1 = WA[2 * ks + 1][1];
          asm("v_permlane32_swap_b32 %0, %1" : "+v"(a0), "+v"(b0));
          asm("v_permlane32_swap_b32 %0, %1" : "+v"(a1), "+v"(b1));
          union { unsigned u[4]; bf16x8 v; } pk;
          pk.u[0] = a0; pk.u[1] = a1; pk.u[2] = b0; pk.u[3] = b1;
          bf16x8 pf = pk.v;
          __builtin_amdgcn_s_setprio(1);
          accsA = MFMA16(pf, ones, accsA);
#pragma unroll
          for (int nt = 0; nt < 4; nt++)
            accA[nt] = MFMA16(pf, vf[nt], accA[nt]);
          __builtin_amdgcn_s_setprio(0);
        }
      }

      __syncthreads();
    }

    // epilogue for both groups (rows quad*4+r; group B rows +64)
    __bf16* opA = O + ((size_t)(b * S_LEN + wq0 + quad * 4)) * HID + h * HD;
    __bf16* opB = opA + (size_t)64 * HID;
    float invA[4], invB[4];
#pragma unroll
    for (int r = 0; r < 4; r++) { invA[r] = rcp_raw(accsA[r]); invB[r] = rcp_raw(accsB[r]); }
#pragma unroll
    for (int nt = 0; nt < 4; nt++)
#pragma unroll
      for (int r = 0; r < 4; r++) {
        opA[(size_t)r * HID + nt * 16 + l15] = (__bf16)(accA[nt][r] * invA[r]);
        opB[(size_t)r * HID + nt * 16 + l15] = (__bf16)(accB[nt][r] * invB[r]);
      }
  }
}

extern "C" void kernel_launch(void* const* d_in, const int* in_sizes, int n_in,
                              void* d_out, int out_size, void* d_ws, size_t ws_size,
                              hipStream_t stream) {
  (void)in_sizes; (void)n_in; (void)out_size; (void)ws_size;
  const float* x  = (const float*)d_in[0];
  const float* fr = (const float*)d_in[1];
  const float* wq = (const float*)d_in[3];
  const float* bq = (const float*)d_in[4];
  const float* wk = (const float*)d_in[5];
  const float* bk = (const float*)d_in[6];
  const float* wv = (const float*)d_in[7];
  const float* bv = (const float*)d_in[8];
  const float* wo = (const float*)d_in[9];
  const float* bo = (const float*)d_in[10];
  float* out = (float*)d_out;
  char* ws = (char*)d_ws;

  __bf16* xb  = (__bf16*)(ws);
  __bf16* wqb = (__bf16*)(ws + ((size_t)16 << 20));
  __bf16* wkb = (__bf16*)(ws + ((size_t)24 << 20));
  __bf16* wvb = (__bf16*)(ws + ((size_t)26 << 20));
  __bf16* wob = (__bf16*)(ws + ((size_t)28 << 20));
  __bf16* Qb  = (__bf16*)(ws + ((size_t)36 << 20));
  __bf16* Kb  = (__bf16*)(ws + ((size_t)52 << 20));
  __bf16* Vtb = (__bf16*)(ws + ((size_t)60 << 20));
  __bf16* Ab  = (__bf16*)(ws + ((size_t)64 << 20));

  cast_all_k<<<18432, 256, 0, stream>>>(x, wq, wk, wv, wo, xb, wqb, wkb, wvb, wob);

  gemm_qkv_k<<<dim3(32, 24), 256, 0, stream>>>(xb, wqb, wkb, wvb, bq, bk, bv, fr, Qb, Kb, Vtb);

  flash_k<<<dim3(64, 8), 256, 0, stream>>>(Qb, Kb, Vtb, fr, Ab);

  gemm_out_k<<<dim3(32, 16), 256, 0, stream>>>(Ab, wob, bo, out);
}

// Round 11
// 288.237 us; speedup vs baseline: 1.2921x; 1.0194x over previous
//
#include <hip/hip_runtime.h>

#define S_LEN 2048
#define HID   2048
#define NQH   32
#define NKV   8
#define HD    64

#define BM 128
#define BN 128
#define BK 32

typedef __bf16 bf16x8 __attribute__((ext_vector_type(8)));
typedef __bf16 bf16x4 __attribute__((ext_vector_type(4)));
typedef float  f32x4  __attribute__((ext_vector_type(4)));

#define MFMA16(a, b, c) __builtin_amdgcn_mfma_f32_16x16x32_bf16(a, b, c, 0, 0, 0)

__device__ __forceinline__ void async_copy16(const void* g, void* l) {
  __builtin_amdgcn_global_load_lds(
      (const __attribute__((address_space(1))) unsigned int*)g,
      (__attribute__((address_space(3))) unsigned int*)l, 16, 0, 0);
}

__device__ __forceinline__ unsigned cvtpk_bf16(float lo, float hi) {
  unsigned r;
  asm("v_cvt_pk_bf16_f32 %0, %1, %2" : "=v"(r) : "v"(lo), "v"(hi));
  return r;
}

// raw v_exp_f32 / v_rcp_f32: skip the denormal-guard libm expansion.
__device__ __forceinline__ float exp2_raw(float x) {
  float r;
  asm("v_exp_f32 %0, %1" : "=v"(r) : "v"(x));
  return r;
}
__device__ __forceinline__ float rcp_raw(float x) {
  float r;
  asm("v_rcp_f32 %0, %1" : "=v"(r) : "v"(x));
  return r;
}

// ---------------- fused f32 -> bf16 cast of x + all weights ----------------
__global__ void cast_all_k(const float* __restrict__ x,  const float* __restrict__ wq,
                           const float* __restrict__ wk, const float* __restrict__ wv,
                           const float* __restrict__ wo,
                           __bf16* __restrict__ xb,  __bf16* __restrict__ wqb,
                           __bf16* __restrict__ wkb, __bf16* __restrict__ wvb,
                           __bf16* __restrict__ wob) {
  int bid = blockIdx.x;
  const float* in; __bf16* out; int base;
  if (bid < 8192)       { in = x;  out = xb;  base = bid; }
  else if (bid < 12288) { in = wq; out = wqb; base = bid - 8192; }
  else if (bid < 13312) { in = wk; out = wkb; base = bid - 12288; }
  else if (bid < 14336) { in = wv; out = wvb; base = bid - 13312; }
  else                  { in = wo; out = wob; base = bid - 14336; }
  int i = (base * 256 + threadIdx.x) * 4;
  float4 v = *(const float4*)(in + i);
  bf16x4 o;
  o[0] = (__bf16)v.x; o[1] = (__bf16)v.y; o[2] = (__bf16)v.z; o[3] = (__bf16)v.w;
  *(bf16x4*)(out + i) = o;
}

// ---------------- 128x128 BK=32 GEMM core, 3-stage counted-vmcnt pipeline ----------------
// unroll 3 matches the 3-stage rotation period: s is compile-time-constant per
// unrolled copy -> LDS bases become immediate offsets (no mod-3 arithmetic).
__device__ __forceinline__ void gemm_pipe(const __bf16* __restrict__ A,
                                          const __bf16* __restrict__ B,
                                          int m0, int n0, int K,
                                          __bf16 (&As)[3][BM][BK],
                                          __bf16 (&Bs)[3][BN][BK],
                                          f32x4 (&acc)[4][4]) {
  const int tid = threadIdx.x, wave = tid >> 6, lane = tid & 63;
  const int l15 = lane & 15, quad = lane >> 4;
  const int wr = wave >> 1, wc = wave & 1;

  const int srow   = tid >> 2;
  const int schunk = (tid & 3) ^ ((tid >> 3) & 3);
  const __bf16* ga = A + (size_t)(m0 + srow) * K + schunk * 8;
  const __bf16* gb = B + (size_t)(n0 + srow) * K + schunk * 8;

  const int co = (quad ^ ((l15 >> 1) & 3)) * 8;

  const int NT = K / BK;

#define STAGE(st, kt) do {                                              \
    async_copy16(ga + (kt),                  &As[st][wave * 16][0]);    \
    async_copy16(ga + (kt) + (size_t)64 * K, &As[st][64 + wave * 16][0]); \
    async_copy16(gb + (kt),                  &Bs[st][wave * 16][0]);    \
    async_copy16(gb + (kt) + (size_t)64 * K, &Bs[st][64 + wave * 16][0]); \
  } while (0)

  STAGE(0, 0);
  STAGE(1, BK);

  int s = 0;
#pragma unroll 3
  for (int t = 0; t < NT; t++) {
    if (t + 1 < NT) asm volatile("s_waitcnt vmcnt(4)" ::: "memory");
    else            asm volatile("s_waitcnt vmcnt(0)" ::: "memory");
    __builtin_amdgcn_s_barrier();
    asm volatile("" ::: "memory");

    if (t + 2 < NT) {
      int s2 = s + 2; if (s2 >= 3) s2 -= 3;
      STAGE(s2, (t + 2) * BK);
    }

    const __bf16* a0 = &As[s][wr * 64][0];
    const __bf16* b0 = &Bs[s][wc * 64][0];
    bf16x8 af[4], bfr[4];
#pragma unroll
    for (int mt = 0; mt < 4; mt++)
      af[mt] = *(const bf16x8*)(a0 + (mt * 16 + l15) * BK + co);
#pragma unroll
    for (int nt = 0; nt < 4; nt++)
      bfr[nt] = *(const bf16x8*)(b0 + (nt * 16 + l15) * BK + co);

    __builtin_amdgcn_s_setprio(1);
#pragma unroll
    for (int mt = 0; mt < 4; mt++)
#pragma unroll
      for (int nt = 0; nt < 4; nt++)
        acc[mt][nt] = MFMA16(af[mt], bfr[nt], acc[mt][nt]);
    __builtin_amdgcn_s_setprio(0);

    s = s + 1; if (s >= 3) s -= 3;
  }
#undef STAGE
}

// fused QKV projection + RoPE(K) + V transpose. grid (32, 24), 256 thr.
__global__ __launch_bounds__(256, 3) void gemm_qkv_k(const __bf16* __restrict__ xb,
    const __bf16* __restrict__ wqb, const __bf16* __restrict__ wkb, const __bf16* __restrict__ wvb,
    const float* __restrict__ bq, const float* __restrict__ bk, const float* __restrict__ bv,
    const float* __restrict__ fr,
    __bf16* __restrict__ Qb, __bf16* __restrict__ Kb, __bf16* __restrict__ Vt) {
  __shared__ __align__(16) __bf16 As[3][BM][BK];
  __shared__ __align__(16) __bf16 Bs[3][BN][BK];
  const int by = blockIdx.y;
  const int m0 = blockIdx.x * BM;
  const __bf16* B; const float* bias; int n0;
  int mode;  // 0 = plain Q, 1 = ropeK, 2 = vtrans
  if (by < 16)      { B = wqb; bias = bq; n0 = by * 128;        mode = 0; }
  else if (by < 20) { B = wkb; bias = bk; n0 = (by - 16) * 128; mode = 1; }
  else              { B = wvb; bias = bv; n0 = (by - 20) * 128; mode = 2; }

  f32x4 acc[4][4] = {};
  gemm_pipe(xb, B, m0, n0, HID, As, Bs, acc);

  const int tid = threadIdx.x, wave = tid >> 6, lane = tid & 63;
  const int l15 = lane & 15, quad = lane >> 4;
  const int wr = wave >> 1, wc = wave & 1;

  if (mode == 2) {
#pragma unroll
    for (int nt = 0; nt < 4; nt++) {
      int col = n0 + wc * 64 + nt * 16 + l15;       // 0..511
      int g = col >> 6, d = col & 63;
      float bv2 = bias[col];
#pragma unroll
      for (int mt = 0; mt < 4; mt++) {
        int row = m0 + wr * 64 + mt * 16 + quad * 4;
        int b = row >> 11, sI = row & 2047;
        bf16x4 o;
#pragma unroll
        for (int r = 0; r < 4; r++) o[r] = (__bf16)(acc[mt][nt][r] + bv2);
        *(bf16x4*)(Vt + (((size_t)(b * NKV + g) * HD + d)) * S_LEN + sI) = o;
      }
    }
  } else if (mode == 0) {
#pragma unroll
    for (int nt = 0; nt < 4; nt++) {
      int col = n0 + wc * 64 + nt * 16 + l15;
      float bv2 = bias[col];
#pragma unroll
      for (int mt = 0; mt < 4; mt++) {
        int row = m0 + wr * 64 + mt * 16 + quad * 4;
#pragma unroll
        for (int r = 0; r < 4; r++)
          Qb[(size_t)(row + r) * HID + col] = (__bf16)(acc[mt][nt][r] + bv2);
      }
    }
  } else {
    const int dpar = l15 & 1;
#pragma unroll
    for (int nt = 0; nt < 4; nt++) {
      int col = n0 + wc * 64 + nt * 16 + l15;
      int d = col & 63;
      float bv2 = bias[col];
#pragma unroll
      for (int mt = 0; mt < 4; mt++) {
        int row = m0 + wr * 64 + mt * 16 + quad * 4;
        int sI = row & 2047;
#pragma unroll
        for (int r = 0; r < 4; r++) {
          float v = acc[mt][nt][r] + bv2;
          float p = __shfl_xor(v, 1, 64);
          float f = fr[(size_t)(sI + r) * HD + d];
          float fp = __shfl_xor(f, 1, 64);
          float o = dpar ? (p * f + v * fp) : (v * f - p * fp);
          Kb[(size_t)(row + r) * 512 + col] = (__bf16)o;
        }
      }
    }
  }
}

// output projection: grid (32, 16) = 512 blocks
__global__ __launch_bounds__(256, 3) void gemm_out_k(const __bf16* __restrict__ A,
    const __bf16* __restrict__ Bw, const float* __restrict__ bias, float* __restrict__ C) {
  __shared__ __align__(16) __bf16 As[3][BM][BK];
  __shared__ __align__(16) __bf16 Bs[3][BN][BK];
  const int m0 = blockIdx.x * BM, n0 = blockIdx.y * BN;
  f32x4 acc[4][4] = {};
  gemm_pipe(A, Bw, m0, n0, HID, As, Bs, acc);
  const int tid = threadIdx.x, wave = tid >> 6, lane = tid & 63;
  const int l15 = lane & 15, quad = lane >> 4;
  const int wr = wave >> 1, wc = wave & 1;
#pragma unroll
  for (int nt = 0; nt < 4; nt++) {
    int col = n0 + wc * 64 + nt * 16 + l15;
    float bv = bias[col];
#pragma unroll
    for (int mt = 0; mt < 4; mt++) {
      int row = m0 + wr * 64 + mt * 16 + quad * 4;
#pragma unroll
      for (int r = 0; r < 4; r++)
        C[(size_t)(row + r) * HID + col] = acc[mt][nt][r] + bv;
    }
  }
}

// RoPE a bf16x8 (pairs 2j,2j+1 adjacent) with contiguous f32 freqs, fused scale.
__device__ __forceinline__ void rope8(bf16x8& q, const float* f, float sc) {
  float4 fa = *(const float4*)f;
  float4 fb = *(const float4*)(f + 4);
  float e, o;
  e = (float)q[0]; o = (float)q[1];
  q[0] = (__bf16)((e * fa.x - o * fa.y) * sc);
  q[1] = (__bf16)((e * fa.y + o * fa.x) * sc);
  e = (float)q[2]; o = (float)q[3];
  q[2] = (__bf16)((e * fa.z - o * fa.w) * sc);
  q[3] = (__bf16)((e * fa.w + o * fa.z) * sc);
  e = (float)q[4]; o = (float)q[5];
  q[4] = (__bf16)((e * fb.x - o * fb.y) * sc);
  q[5] = (__bf16)((e * fb.y + o * fb.x) * sc);
  e = (float)q[6]; o = (float)q[7];
  q[6] = (__bf16)((e * fb.z - o * fb.w) * sc);
  q[7] = (__bf16)((e * fb.w + o * fb.z) * sc);
}

// ---------------- Flash attention v10 (known-good, round-9 293.8us config) ----------------
__global__ __launch_bounds__(256, 2) void flash_k(const __bf16* __restrict__ Q,
                                                  const __bf16* __restrict__ K,
                                                  const __bf16* __restrict__ Vt,
                                                  const float* __restrict__ fr,
                                                  __bf16* __restrict__ O) {
  __shared__ __align__(64) __bf16 Ksm[2][64][64];    // [buf][kv][d] swizzled (key=row&7)
  __shared__ __align__(64) __bf16 Vsm[2][64][64];    // [buf][d][kv] swizzled
  const int tid = threadIdx.x;
  const int wave = tid >> 6, lane = tid & 63;
  const int l15 = lane & 15, quad = lane >> 4;
  const int bh = blockIdx.x;
  const int b = bh >> 5, h = bh & 31, g = h >> 2;

  const int srow = tid >> 2, sc = (tid & 3) * 16;
  const int r7 = srow & 7;
  const int w0 = (((sc >> 3))     ^ r7) * 8;
  const int w1 = (((sc >> 3) + 1) ^ r7) * 8;

  const char* kbp = (const char*)&Ksm[0][0][0];
  const char* vbp = (const char*)&Vsm[0][0][0];

  const int x7  = l15 & 7;
  const int sig = 8 * ((l15 >> 2) & 1) + 4 * (l15 >> 3) + (l15 & 3);
  const int s7  = sig & 7;
  int krK[2], krV[2];
#pragma unroll
  for (int ks = 0; ks < 2; ks++) {
    krK[ks] = sig * 128 + (((ks * 4 + quad) ^ s7) * 16);
    krV[ks] = l15 * 128 + (((ks * 4 + quad) ^ x7) * 16);
  }
  const int kvb = 8 * (quad & 1) + 4 * (quad >> 1);

  bf16x8 ones;
#pragma unroll
  for (int j = 0; j < 8; j++) ones[j] = (__bf16)1.0f;

  const __bf16* kbase = K + ((size_t)b * S_LEN + srow) * (NKV * HD) + g * HD + sc;
  const __bf16* vbase = Vt + (((size_t)b * NKV + g) * HD + srow) * S_LEN + sc;
  const float QSC = 0.125f * 1.44269504f;   // 1/sqrt(64) * log2(e)
  const int KSTEP = 64 * NKV * HD;

#pragma unroll 1
  for (int half = 0; half < 2; half++) {
    const int qt = half ? (15 - (int)blockIdx.y) : (int)blockIdx.y;
    const int NT = 2 * qt + 2;                 // kv tiles for this q-tile
    const int wq0 = qt * 128 + wave * 16;      // group A rows; group B = +64

    const __bf16* qpA = Q + ((size_t)(b * S_LEN + wq0 + l15)) * HID + h * HD + quad * 8;
    const __bf16* qpB = qpA + (size_t)64 * HID;
    bf16x8 qfA0 = *(const bf16x8*)qpA;
    bf16x8 qfA1 = *(const bf16x8*)(qpA + 32);
    bf16x8 qfB0 = *(const bf16x8*)qpB;
    bf16x8 qfB1 = *(const bf16x8*)(qpB + 32);
    const float* fqA = fr + (size_t)(wq0 + l15) * HD + quad * 8;
    const float* fqB = fqA + (size_t)64 * HD;
    rope8(qfA0, fqA, QSC);
    rope8(qfA1, fqA + 32, QSC);
    rope8(qfB0, fqB, QSC);
    rope8(qfB1, fqB + 32, QSC);

    f32x4 accA[4] = {}, accB[4] = {};
    f32x4 accsA = {}, accsB = {};

    const __bf16* kp = kbase;
    const __bf16* vp = vbase;
    uint4 k0 = *(const uint4*)kp, k1 = *(const uint4*)(kp + 8);
    uint4 v0 = *(const uint4*)vp, v1 = *(const uint4*)(vp + 8);
    *(uint4*)&Ksm[0][srow][w0] = k0;
    *(uint4*)&Ksm[0][srow][w1] = k1;
    *(uint4*)&Vsm[0][srow][w0] = v0;
    *(uint4*)&Vsm[0][srow][w1] = v1;
    // NT >= 2 always: prefetch tile 1
    kp += KSTEP;  vp += 64;
    k0 = *(const uint4*)kp; k1 = *(const uint4*)(kp + 8);
    v0 = *(const uint4*)vp; v1 = *(const uint4*)(vp + 8);
    __syncthreads();

#pragma unroll 1
    for (int t = 0; t < NT; t++) {
      const int cur = t & 1;
      const int kv0 = t * 64;

      if (t + 1 < NT) {
        *(uint4*)&Ksm[cur ^ 1][srow][w0] = k0;
        *(uint4*)&Ksm[cur ^ 1][srow][w1] = k1;
        *(uint4*)&Vsm[cur ^ 1][srow][w0] = v0;
        *(uint4*)&Vsm[cur ^ 1][srow][w1] = v1;
        if (t + 2 < NT) {
          kp += KSTEP;  vp += 64;
          k0 = *(const uint4*)kp; k1 = *(const uint4*)(kp + 8);
          v0 = *(const uint4*)vp; v1 = *(const uint4*)(vp + 8);
        }
      }

      const bool actA = (kv0 <= wq0 + 15);   // group A not fully masked (uniform/wave)
      const int cb = cur * 8192;

      bf16x8 kf[2][4];
#pragma unroll
      for (int ks = 0; ks < 2; ks++)
#pragma unroll
        for (int nt = 0; nt < 4; nt++)
          kf[ks][nt] = *(const bf16x8*)(kbp + cb + krK[ks] + nt * 2048);

      // ---- group B scores (always active; B q-rows = wq0+64..) ----
      unsigned WB[4][2];
      {
        f32x4 sacc[4] = {};
        __builtin_amdgcn_s_setprio(1);
#pragma unroll
        for (int nt = 0; nt < 4; nt++) {
          sacc[nt] = MFMA16(kf[0][nt], qfB0, sacc[nt]);
          sacc[nt] = MFMA16(kf[1][nt], qfB1, sacc[nt]);
        }
        __builtin_amdgcn_s_setprio(0);
        const int wq0B = wq0 + 64;
        const bool domask = (kv0 + 63 > wq0B);
        const int md = wq0B + l15 - kv0 - kvb;
#pragma unroll
        for (int nt = 0; nt < 4; nt++) {
          f32x4 pv;
#pragma unroll
          for (int r = 0; r < 4; r++) pv[r] = exp2_raw(sacc[nt][r]);
          if (domask) {
#pragma unroll
            for (int r = 0; r < 4; r++)
              if (nt * 16 + r > md) pv[r] = 0.f;
          }
          WB[nt][0] = cvtpk_bf16(pv[0], pv[1]);
          WB[nt][1] = cvtpk_bf16(pv[2], pv[3]);
        }
      }
      // ---- group A scores ----
      unsigned WA[4][2];
      if (actA) {
        f32x4 sacc[4] = {};
        __builtin_amdgcn_s_setprio(1);
#pragma unroll
        for (int nt = 0; nt < 4; nt++) {
          sacc[nt] = MFMA16(kf[0][nt], qfA0, sacc[nt]);
          sacc[nt] = MFMA16(kf[1][nt], qfA1, sacc[nt]);
        }
        __builtin_amdgcn_s_setprio(0);
        const bool domask = (kv0 + 63 > wq0);
        const int md = wq0 + l15 - kv0 - kvb;
#pragma unroll
        for (int nt = 0; nt < 4; nt++) {
          f32x4 pv;
#pragma unroll
          for (int r = 0; r < 4; r++) pv[r] = exp2_raw(sacc[nt][r]);
          if (domask) {
#pragma unroll
            for (int r = 0; r < 4; r++)
              if (nt * 16 + r > md) pv[r] = 0.f;
          }
          WA[nt][0] = cvtpk_bf16(pv[0], pv[1]);
          WA[nt][1] = cvtpk_bf16(pv[2], pv[3]);
        }
      }

      // ---- PV for both groups; vf read once ----
#pragma unroll
      for (int ks = 0; ks < 2; ks++) {
        bf16x8 vf[4];
#pragma unroll
        for (int nt = 0; nt < 4; nt++)
          vf[nt] = *(const bf16x8*)(vbp + cb + krV[ks] + nt * 2048);

        {
          unsigned a0 = WB[2 * ks][0], b0 = WB[2 * ks + 1][0];
          unsigned a1 = WB[2 * ks][1], b1 = WB[2 * ks + 1][1];
          asm("v_permlane32_swap_b32 %0, %1" : "+v"(a0), "+v"(b0));
          asm("v_permlane32_swap_b32 %0, %1" : "+v"(a1), "+v"(b1));
          union { unsigned u[4]; bf16x8 v; } pk;
          pk.u[0] = a0; pk.u[1] = a1; pk.u[2] = b0; pk.u[3] = b1;
          bf16x8 pf = pk.v;
          __builtin_amdgcn_s_setprio(1);
          accsB = MFMA16(pf, ones, accsB);
#pragma unroll
          for (int nt = 0; nt < 4; nt++)
            accB[nt] = MFMA16(pf, vf[nt], accB[nt]);
          __builtin_amdgcn_s_setprio(0);
        }
        if (actA) {
          unsigned a0 = WA[2 * ks][0], b0 = WA[2 * ks + 1][0];
          unsigned a1 = WA[2 * ks][1], b1 = WA[2 * ks + 1][1];
          asm("v_permlane32_swap_b32 %0, %1" : "+v"(a0), "+v"(b0));
          asm("v_permlane32_swap_b32 %0, %1" : "+v"(a1), "+v"(b1));
          union { unsigned u[4]; bf16x8 v; } pk;
          pk.u[0] = a0; pk.u[1] = a1; pk.u[2] = b0; pk.u[3] = b1;
          bf16x8 pf = pk.v;
          __builtin_amdgcn_s_setprio(1);
          accsA = MFMA16(pf, ones, accsA);
#pragma unroll
          for (int nt = 0; nt < 4; nt++)
            accA[nt] = MFMA16(pf, vf[nt], accA[nt]);
          __builtin_amdgcn_s_setprio(0);
        }
      }

      __syncthreads();
    }

    // epilogue for both groups (rows quad*4+r; group B rows +64)
    __bf16* opA = O + ((size_t)(b * S_LEN + wq0 + quad * 4)) * HID + h * HD;
    __bf16* opB = opA + (size_t)64 * HID;
    float invA[4], invB[4];
#pragma unroll
    for (int r = 0; r < 4; r++) { invA[r] = rcp_raw(accsA[r]); invB[r] = rcp_raw(accsB[r]); }
#pragma unroll
    for (int nt = 0; nt < 4; nt++)
#pragma unroll
      for (int r = 0; r < 4; r++) {
        opA[(size_t)r * HID + nt * 16 + l15] = (__bf16)(accA[nt][r] * invA[r]);
        opB[(size_t)r * HID + nt * 16 + l15] = (__bf16)(accB[nt][r] * invB[r]);
      }
  }
}

extern "C" void kernel_launch(void* const* d_in, const int* in_sizes, int n_in,
                              void* d_out, int out_size, void* d_ws, size_t ws_size,
                              hipStream_t stream) {
  (void)in_sizes; (void)n_in; (void)out_size; (void)ws_size;
  const float* x  = (const float*)d_in[0];
  const float* fr = (const float*)d_in[1];
  const float* wq = (const float*)d_in[3];
  const float* bq = (const float*)d_in[4];
  const float* wk = (const float*)d_in[5];
  const float* bk = (const float*)d_in[6];
  const float* wv = (const float*)d_in[7];
  const float* bv = (const float*)d_in[8];
  const float* wo = (const float*)d_in[9];
  const float* bo = (const float*)d_in[10];
  float* out = (float*)d_out;
  char* ws = (char*)d_ws;

  __bf16* xb  = (__bf16*)(ws);
  __bf16* wqb = (__bf16*)(ws + ((size_t)16 << 20));
  __bf16* wkb = (__bf16*)(ws + ((size_t)24 << 20));
  __bf16* wvb = (__bf16*)(ws + ((size_t)26 << 20));
  __bf16* wob = (__bf16*)(ws + ((size_t)28 << 20));
  __bf16* Qb  = (__bf16*)(ws + ((size_t)36 << 20));
  __bf16* Kb  = (__bf16*)(ws + ((size_t)52 << 20));
  __bf16* Vtb = (__bf16*)(ws + ((size_t)60 << 20));
  __bf16* Ab  = (__bf16*)(ws + ((size_t)64 << 20));

  cast_all_k<<<18432, 256, 0, stream>>>(x, wq, wk, wv, wo, xb, wqb, wkb, wvb, wob);

  gemm_qkv_k<<<dim3(32, 24), 256, 0, stream>>>(xb, wqb, wkb, wvb, bq, bk, bv, fr, Qb, Kb, Vtb);

  flash_k<<<dim3(64, 8), 256, 0, stream>>>(Qb, Kb, Vtb, fr, Ab);

  gemm_out_k<<<dim3(32, 16), 256, 0, stream>>>(Ab, wob, bo, out);
}